// Round 5
// baseline (5767.241 us; speedup 1.0000x reference)
//
#include <hip/hip_runtime.h>

#define NU 200000
#define NM 100000
#define NE 4000000
#define D  64

#define BDST 128                       // destinations per bucket (dst >> 7)
#define BU_BKTS ((NU + BDST - 1) / BDST)   // 1563 user buckets
#define BM_BKTS ((NM + BDST - 1) / BDST)   // 782 movie buckets
#define NBKT (BU_BKTS + BM_BKTS)       // 2345
#define NBLK 256                       // partition blocking (NE % NBLK == 0)
#define CHUNK (NE / NBLK)              // 15625 edges per block

// ---------------------------------------------------------------------------
// K1: per-block bucket histogram (both directions), LDS atomics only.
// C_u[blk][b], C_m[blk][b] = count of this block's edges landing in bucket b.
// ---------------------------------------------------------------------------
__global__ __launch_bounds__(256) void hist_k(const int* __restrict__ uidx,
                                              const int* __restrict__ midx,
                                              int* __restrict__ C_u,
                                              int* __restrict__ C_m) {
  __shared__ int h[NBKT];
  for (int i = threadIdx.x; i < NBKT; i += 256) h[i] = 0;
  __syncthreads();
  const int base = blockIdx.x * CHUNK;
  for (int e = base + threadIdx.x; e < base + CHUNK; e += 256) {
    atomicAdd(&h[uidx[e] >> 7], 1);
    atomicAdd(&h[BU_BKTS + (midx[e] >> 7)], 1);
  }
  __syncthreads();
  for (int i = threadIdx.x; i < BU_BKTS; i += 256) C_u[blockIdx.x * BU_BKTS + i] = h[i];
  for (int i = threadIdx.x; i < BM_BKTS; i += 256) C_m[blockIdx.x * BM_BKTS + i] = h[BU_BKTS + i];
}

// ---------------------------------------------------------------------------
// K2a: per-bucket exclusive prefix over blocks (in place); emit bucket totals.
// ---------------------------------------------------------------------------
__global__ __launch_bounds__(256) void colscan_k(int* __restrict__ C_u,
                                                 int* __restrict__ C_m,
                                                 int* __restrict__ tot_u,
                                                 int* __restrict__ tot_m) {
  const int t = blockIdx.x * blockDim.x + threadIdx.x;
  if (t < BU_BKTS) {
    int run = 0;
    for (int blk = 0; blk < NBLK; ++blk) {
      const int idx = blk * BU_BKTS + t;
      const int v = C_u[idx];
      C_u[idx] = run;
      run += v;
    }
    tot_u[t] = run;
  } else if (t < NBKT) {
    const int b = t - BU_BKTS;
    int run = 0;
    for (int blk = 0; blk < NBLK; ++blk) {
      const int idx = blk * BM_BKTS + b;
      const int v = C_m[idx];
      C_m[idx] = run;
      run += v;
    }
    tot_m[b] = run;
  }
}

// ---------------------------------------------------------------------------
// K2b: single-block exclusive scans of bucket totals -> bucket bases.
// ---------------------------------------------------------------------------
__device__ void scan_inline(const int* __restrict__ in, int* __restrict__ out,
                            int n, int* partial) {
  const int tid = threadIdx.x;
  const int chunk = (n + 1023) / 1024;
  const int s = tid * chunk;
  const int e = min(s + chunk, n);
  int sum = 0;
  for (int i = s; i < e; ++i) sum += in[i];
  partial[tid] = sum;
  __syncthreads();
  for (int off = 1; off < 1024; off <<= 1) {
    int v = (tid >= off) ? partial[tid - off] : 0;
    __syncthreads();
    if (tid >= off) partial[tid] += v;
    __syncthreads();
  }
  int run = (tid == 0) ? 0 : partial[tid - 1];
  for (int i = s; i < e; ++i) {
    out[i] = run;
    run += in[i];
  }
  if (tid == 1023) out[n] = partial[1023];
}

__global__ __launch_bounds__(1024) void bucketscan_k(const int* __restrict__ tot_u,
                                                     int* __restrict__ bb_u,
                                                     const int* __restrict__ tot_m,
                                                     int* __restrict__ bb_m) {
  __shared__ int partial[1024];
  scan_inline(tot_u, bb_u, BU_BKTS, partial);
  __syncthreads();
  scan_inline(tot_m, bb_m, BM_BKTS, partial);
}

// ---------------------------------------------------------------------------
// K3: partition pass. cursor[b] = bb[b] + C[blk][b]; every record position is
// claimed with an LDS atomic (no global atomics). rec = (src << 7) | dstlow.
// ---------------------------------------------------------------------------
__global__ __launch_bounds__(256) void part_k(const int* __restrict__ uidx,
                                              const int* __restrict__ midx,
                                              const int* __restrict__ C_u,
                                              const int* __restrict__ C_m,
                                              const int* __restrict__ bb_u,
                                              const int* __restrict__ bb_m,
                                              int* __restrict__ rec_u,
                                              int* __restrict__ rec_m) {
  __shared__ int cur[NBKT];
  for (int i = threadIdx.x; i < BU_BKTS; i += 256)
    cur[i] = bb_u[i] + C_u[blockIdx.x * BU_BKTS + i];
  for (int i = threadIdx.x; i < BM_BKTS; i += 256)
    cur[BU_BKTS + i] = bb_m[i] + C_m[blockIdx.x * BM_BKTS + i];
  __syncthreads();
  const int base = blockIdx.x * CHUNK;
  for (int e = base + threadIdx.x; e < base + CHUNK; e += 256) {
    const int u = uidx[e];
    const int m = midx[e];
    const int pu = atomicAdd(&cur[u >> 7], 1);
    rec_u[pu] = (m << 7) | (u & (BDST - 1));
    const int pm = atomicAdd(&cur[BU_BKTS + (m >> 7)], 1);
    rec_m[pm] = (u << 7) | (m & (BDST - 1));
  }
}

// ---------------------------------------------------------------------------
// Fused layer: one block per bucket. Phase 1: gather x[src] rows, accumulate
// into LDS acc[128][64] (ds_add_f32, conflict-free) + LDS edge counts.
// Phase 2: mean -> readlane/FMA SAGE transform -> final output write.
// Blocks [0, BM_BKTS) update movies; [BM_BKTS, NBKT) update users.
// ---------------------------------------------------------------------------
__global__ __launch_bounds__(256) void fused_layer_k(
    const float* __restrict__ xsrc_for_m,  // features of users (sources for movie dst)
    const float* __restrict__ xsrc_for_u,  // features of movies (sources for user dst)
    const float* __restrict__ xdst_m, const float* __restrict__ xdst_u,
    const int* __restrict__ rec_m, const int* __restrict__ rec_u,
    const int* __restrict__ bb_m, const int* __restrict__ bb_u,
    const float* __restrict__ Wl_um, const float* __restrict__ b_um,
    const float* __restrict__ Wr_um,
    const float* __restrict__ Wl_mu, const float* __restrict__ b_mu,
    const float* __restrict__ Wr_mu,
    float* __restrict__ out_m, float* __restrict__ out_u, int do_relu) {
  __shared__ float acc[BDST][D];
  __shared__ int cnt[BDST];

  const int lane = threadIdx.x & 63;
  const int wv = threadIdx.x >> 6;  // wave id 0..3
  const bool is_m = (blockIdx.x < BM_BKTS);
  const int bkt = is_m ? blockIdx.x : blockIdx.x - BM_BKTS;

  const float* xsrc = is_m ? xsrc_for_m : xsrc_for_u;
  const float* xdst = is_m ? xdst_m : xdst_u;
  const int* recs = is_m ? rec_m : rec_u;
  const int* bb = is_m ? bb_m : bb_u;
  const float* Wl = is_m ? Wl_um : Wl_mu;
  const float* Wr = is_m ? Wr_um : Wr_mu;
  const float* bias = is_m ? b_um : b_mu;
  float* out = is_m ? out_m : out_u;
  const int nDst = is_m ? NM : NU;

  // zero LDS accumulators
  for (int i = threadIdx.x; i < BDST * D; i += 256) ((float*)acc)[i] = 0.f;
  for (int i = threadIdx.x; i < BDST; i += 256) cnt[i] = 0;
  __syncthreads();

  // ---- phase 1: gather + LDS accumulate (low register pressure) ----
  const int rbeg = bb[bkt];
  const int rend = bb[bkt + 1];
  const int len = rend - rbeg;
  const int nper = (len + 3) >> 2;
  const int ws = rbeg + wv * nper;
  const int we = min(ws + nper, rend);

  int j = ws;
  for (; j + 8 <= we; j += 8) {
    const int q0 = recs[j],     q1 = recs[j + 1], q2 = recs[j + 2], q3 = recs[j + 3];
    const int q4 = recs[j + 4], q5 = recs[j + 5], q6 = recs[j + 6], q7 = recs[j + 7];
    const float v0 = xsrc[(size_t)(q0 >> 7) * D + lane];
    const float v1 = xsrc[(size_t)(q1 >> 7) * D + lane];
    const float v2 = xsrc[(size_t)(q2 >> 7) * D + lane];
    const float v3 = xsrc[(size_t)(q3 >> 7) * D + lane];
    const float v4 = xsrc[(size_t)(q4 >> 7) * D + lane];
    const float v5 = xsrc[(size_t)(q5 >> 7) * D + lane];
    const float v6 = xsrc[(size_t)(q6 >> 7) * D + lane];
    const float v7 = xsrc[(size_t)(q7 >> 7) * D + lane];
    atomicAdd(&acc[q0 & (BDST - 1)][lane], v0);
    atomicAdd(&acc[q1 & (BDST - 1)][lane], v1);
    atomicAdd(&acc[q2 & (BDST - 1)][lane], v2);
    atomicAdd(&acc[q3 & (BDST - 1)][lane], v3);
    atomicAdd(&acc[q4 & (BDST - 1)][lane], v4);
    atomicAdd(&acc[q5 & (BDST - 1)][lane], v5);
    atomicAdd(&acc[q6 & (BDST - 1)][lane], v6);
    atomicAdd(&acc[q7 & (BDST - 1)][lane], v7);
    if (lane == 0) {
      atomicAdd(&cnt[q0 & (BDST - 1)], 1);
      atomicAdd(&cnt[q1 & (BDST - 1)], 1);
      atomicAdd(&cnt[q2 & (BDST - 1)], 1);
      atomicAdd(&cnt[q3 & (BDST - 1)], 1);
      atomicAdd(&cnt[q4 & (BDST - 1)], 1);
      atomicAdd(&cnt[q5 & (BDST - 1)], 1);
      atomicAdd(&cnt[q6 & (BDST - 1)], 1);
      atomicAdd(&cnt[q7 & (BDST - 1)], 1);
    }
  }
  for (; j < we; ++j) {
    const int q = recs[j];
    const float v = xsrc[(size_t)(q >> 7) * D + lane];
    atomicAdd(&acc[q & (BDST - 1)][lane], v);
    if (lane == 0) atomicAdd(&cnt[q & (BDST - 1)], 1);
  }

  __syncthreads();

  // ---- phase 2: load weight columns, transform, write final output ----
  float wl[D], wr[D];
#pragma unroll
  for (int k = 0; k < D; ++k) {
    wl[k] = Wl[k * D + lane];
    wr[k] = Wr[k * D + lane];
  }
  const float bias_v = bias[lane];

  for (int s = wv; s < BDST; s += 4) {
    const int node = bkt * BDST + s;
    if (node >= nDst) break;
    const float c = (float)cnt[s];
    const float inv = 1.0f / fmaxf(c, 1.0f);
    const float mean = acc[s][lane] * inv;
    const float xv = xdst[(size_t)node * D + lane];

    float a0 = 0.f, a1 = 0.f, a2 = 0.f, a3 = 0.f;
#pragma unroll
    for (int k = 0; k < D; k += 2) {
      const float mk0 = __uint_as_float(__builtin_amdgcn_readlane(__float_as_uint(mean), k));
      const float xk0 = __uint_as_float(__builtin_amdgcn_readlane(__float_as_uint(xv),   k));
      const float mk1 = __uint_as_float(__builtin_amdgcn_readlane(__float_as_uint(mean), k + 1));
      const float xk1 = __uint_as_float(__builtin_amdgcn_readlane(__float_as_uint(xv),   k + 1));
      a0 = fmaf(mk0, wl[k],     a0);
      a1 = fmaf(xk0, wr[k],     a1);
      a2 = fmaf(mk1, wl[k + 1], a2);
      a3 = fmaf(xk1, wr[k + 1], a3);
    }
    float res = bias_v + a0 + a1 + a2 + a3;
    if (do_relu) res = fmaxf(res, 0.f);
    out[(size_t)node * D + lane] = res;
  }
}

// ---------------------------------------------------------------------------
extern "C" void kernel_launch(void* const* d_in, const int* in_sizes, int n_in,
                              void* d_out, int out_size, void* d_ws, size_t ws_size,
                              hipStream_t stream) {
  const float* x_user  = (const float*)d_in[0];
  const float* x_movie = (const float*)d_in[1];
  const float* Wl1_um = (const float*)d_in[2];
  const float* Wr1_um = (const float*)d_in[3];
  const float* b1_um  = (const float*)d_in[4];
  const float* Wl1_mu = (const float*)d_in[5];
  const float* Wr1_mu = (const float*)d_in[6];
  const float* b1_mu  = (const float*)d_in[7];
  const float* Wl2_um = (const float*)d_in[8];
  const float* Wr2_um = (const float*)d_in[9];
  const float* b2_um  = (const float*)d_in[10];
  const float* Wl2_mu = (const float*)d_in[11];
  const float* Wr2_mu = (const float*)d_in[12];
  const float* b2_mu  = (const float*)d_in[13];
  const int* uidx = (const int*)d_in[14];
  const int* midx = (const int*)d_in[15];

  // workspace layout
  char* ws = (char*)d_ws;
  float* u1   = (float*)ws;  ws += (size_t)NU * D * sizeof(float);      // 51.2 MB
  float* m1   = (float*)ws;  ws += (size_t)NM * D * sizeof(float);      // 25.6 MB
  int* rec_u  = (int*)ws;    ws += (size_t)NE * sizeof(int);            // 16 MB
  int* rec_m  = (int*)ws;    ws += (size_t)NE * sizeof(int);            // 16 MB
  int* C_u    = (int*)ws;    ws += (size_t)NBLK * BU_BKTS * sizeof(int);// 1.6 MB
  int* C_m    = (int*)ws;    ws += (size_t)NBLK * BM_BKTS * sizeof(int);// 0.8 MB
  int* tot_u  = (int*)ws;    ws += (size_t)BU_BKTS * sizeof(int);
  int* tot_m  = (int*)ws;    ws += (size_t)BM_BKTS * sizeof(int);
  int* bb_u   = (int*)ws;    ws += ((size_t)BU_BKTS + 1) * sizeof(int);
  int* bb_m   = (int*)ws;    ws += ((size_t)BM_BKTS + 1) * sizeof(int);

  float* u2 = (float*)d_out;                    // users first in concat
  float* m2 = (float*)d_out + (size_t)NU * D;   // then movies

  const dim3 blk(256);

  // ---- bucket partition build (graph identical for both layers) ----
  hist_k<<<NBLK, blk, 0, stream>>>(uidx, midx, C_u, C_m);
  colscan_k<<<(NBKT + 255) / 256, blk, 0, stream>>>(C_u, C_m, tot_u, tot_m);
  bucketscan_k<<<1, 1024, 0, stream>>>(tot_u, bb_u, tot_m, bb_m);
  part_k<<<NBLK, blk, 0, stream>>>(uidx, midx, C_u, C_m, bb_u, bb_m, rec_u, rec_m);

  // ---- layer 1 (relu) ----
  fused_layer_k<<<NBKT, blk, 0, stream>>>(x_user, x_movie, x_movie, x_user,
                                          rec_m, rec_u, bb_m, bb_u,
                                          Wl1_um, b1_um, Wr1_um,
                                          Wl1_mu, b1_mu, Wr1_mu,
                                          m1, u1, 1);

  // ---- layer 2 (no activation, write d_out) ----
  fused_layer_k<<<NBKT, blk, 0, stream>>>(u1, m1, m1, u1,
                                          rec_m, rec_u, bb_m, bb_u,
                                          Wl2_um, b2_um, Wr2_um,
                                          Wl2_mu, b2_mu, Wr2_mu,
                                          m2, u2, 0);
}

// Round 6
// 1160.616 us; speedup vs baseline: 4.9691x; 4.9691x over previous
//
#include <hip/hip_runtime.h>

#define NU 200000
#define NM 100000
#define NE 4000000
#define D  64

#define BDST 128                           // destinations per bucket (dst >> 7)
#define BU_BKTS ((NU + BDST - 1) / BDST)   // 1563 user buckets
#define BM_BKTS ((NM + BDST - 1) / BDST)   // 782 movie buckets
#define NBKT (BU_BKTS + BM_BKTS)           // 2345
#define NBLK 1024                          // partition blocking
#define CHUNK ((NE + NBLK - 1) / NBLK)     // 3907

// ---------------------------------------------------------------------------
// K1: per-block bucket histogram (both directions), LDS atomics only.
// ---------------------------------------------------------------------------
__global__ __launch_bounds__(256) void hist_k(const int* __restrict__ uidx,
                                              const int* __restrict__ midx,
                                              int* __restrict__ C_u,
                                              int* __restrict__ C_m) {
  __shared__ int h[NBKT];
  for (int i = threadIdx.x; i < NBKT; i += 256) h[i] = 0;
  __syncthreads();
  const int base = blockIdx.x * CHUNK;
  const int lim = min(base + CHUNK, NE);
  for (int e = base + threadIdx.x; e < lim; e += 256) {
    atomicAdd(&h[uidx[e] >> 7], 1);
    atomicAdd(&h[BU_BKTS + (midx[e] >> 7)], 1);
  }
  __syncthreads();
  for (int i = threadIdx.x; i < BU_BKTS; i += 256) C_u[(size_t)blockIdx.x * BU_BKTS + i] = h[i];
  for (int i = threadIdx.x; i < BM_BKTS; i += 256) C_m[(size_t)blockIdx.x * BM_BKTS + i] = h[BU_BKTS + i];
}

// ---------------------------------------------------------------------------
// K2a: per-bucket exclusive prefix over blocks (in place); emit bucket totals.
// ---------------------------------------------------------------------------
__global__ __launch_bounds__(256) void colscan_k(int* __restrict__ C_u,
                                                 int* __restrict__ C_m,
                                                 int* __restrict__ tot_u,
                                                 int* __restrict__ tot_m) {
  const int t = blockIdx.x * blockDim.x + threadIdx.x;
  if (t < BU_BKTS) {
    int run = 0;
    for (int blk = 0; blk < NBLK; ++blk) {
      const size_t idx = (size_t)blk * BU_BKTS + t;
      const int v = C_u[idx];
      C_u[idx] = run;
      run += v;
    }
    tot_u[t] = run;
  } else if (t < NBKT) {
    const int b = t - BU_BKTS;
    int run = 0;
    for (int blk = 0; blk < NBLK; ++blk) {
      const size_t idx = (size_t)blk * BM_BKTS + b;
      const int v = C_m[idx];
      C_m[idx] = run;
      run += v;
    }
    tot_m[b] = run;
  }
}

// ---------------------------------------------------------------------------
// K2b: single-block exclusive scans of bucket totals -> bucket bases.
// ---------------------------------------------------------------------------
__device__ void scan_inline(const int* __restrict__ in, int* __restrict__ out,
                            int n, int* partial) {
  const int tid = threadIdx.x;
  const int chunk = (n + 1023) / 1024;
  const int s = tid * chunk;
  const int e = min(s + chunk, n);
  int sum = 0;
  for (int i = s; i < e; ++i) sum += in[i];
  partial[tid] = sum;
  __syncthreads();
  for (int off = 1; off < 1024; off <<= 1) {
    int v = (tid >= off) ? partial[tid - off] : 0;
    __syncthreads();
    if (tid >= off) partial[tid] += v;
    __syncthreads();
  }
  int run = (tid == 0) ? 0 : partial[tid - 1];
  for (int i = s; i < e; ++i) {
    out[i] = run;
    run += in[i];
  }
  if (tid == 1023) out[n] = partial[1023];
}

__global__ __launch_bounds__(1024) void bucketscan_k(const int* __restrict__ tot_u,
                                                     int* __restrict__ bb_u,
                                                     const int* __restrict__ tot_m,
                                                     int* __restrict__ bb_m) {
  __shared__ int partial[1024];
  scan_inline(tot_u, bb_u, BU_BKTS, partial);
  __syncthreads();
  scan_inline(tot_m, bb_m, BM_BKTS, partial);
}

// ---------------------------------------------------------------------------
// K3: partition pass. cursor[b] = bb[b] + C[blk][b]; positions claimed with
// LDS atomics only. rec = (src << 7) | dstlow.
// ---------------------------------------------------------------------------
__global__ __launch_bounds__(256) void part_k(const int* __restrict__ uidx,
                                              const int* __restrict__ midx,
                                              const int* __restrict__ C_u,
                                              const int* __restrict__ C_m,
                                              const int* __restrict__ bb_u,
                                              const int* __restrict__ bb_m,
                                              int* __restrict__ rec_u,
                                              int* __restrict__ rec_m) {
  __shared__ int cur[NBKT];
  for (int i = threadIdx.x; i < BU_BKTS; i += 256)
    cur[i] = bb_u[i] + C_u[(size_t)blockIdx.x * BU_BKTS + i];
  for (int i = threadIdx.x; i < BM_BKTS; i += 256)
    cur[BU_BKTS + i] = bb_m[i] + C_m[(size_t)blockIdx.x * BM_BKTS + i];
  __syncthreads();
  const int base = blockIdx.x * CHUNK;
  const int lim = min(base + CHUNK, NE);
  for (int e = base + threadIdx.x; e < lim; e += 256) {
    const int u = uidx[e];
    const int m = midx[e];
    const int pu = atomicAdd(&cur[u >> 7], 1);
    rec_u[pu] = (m << 7) | (u & (BDST - 1));
    const int pm = atomicAdd(&cur[BU_BKTS + (m >> 7)], 1);
    rec_m[pm] = (u << 7) | (m & (BDST - 1));
  }
}

// ---------------------------------------------------------------------------
// K4: per-bucket counting sort -> per-node CSR (adj + rowp). LDS atomics only.
// Blocks [0, BM_BKTS) sort movie buckets; [BM_BKTS, NBKT) user buckets.
// ---------------------------------------------------------------------------
__global__ __launch_bounds__(256) void sort_k(const int* __restrict__ rec_m,
                                              const int* __restrict__ rec_u,
                                              const int* __restrict__ bb_m,
                                              const int* __restrict__ bb_u,
                                              int* __restrict__ adj_m,
                                              int* __restrict__ adj_u,
                                              int* __restrict__ rowp_m,
                                              int* __restrict__ rowp_u) {
  __shared__ int cnt[BDST];
  __shared__ int off[BDST];
  __shared__ int tmp[BDST];
  const bool is_m = (blockIdx.x < BM_BKTS);
  const int bkt = is_m ? blockIdx.x : blockIdx.x - BM_BKTS;
  const int* recs = is_m ? rec_m : rec_u;
  const int* bb   = is_m ? bb_m : bb_u;
  int* adj  = is_m ? adj_m : adj_u;
  int* rowp = is_m ? rowp_m : rowp_u;
  const int nDst = is_m ? NM : NU;
  const int tid = threadIdx.x;

  for (int i = tid; i < BDST; i += 256) cnt[i] = 0;
  __syncthreads();
  const int rbeg = bb[bkt], rend = bb[bkt + 1];
  for (int j = rbeg + tid; j < rend; j += 256)
    atomicAdd(&cnt[recs[j] & (BDST - 1)], 1);
  __syncthreads();

  // exclusive scan of cnt[0..127] -> off (Hillis-Steele; all threads sync)
  if (tid < BDST) tmp[tid] = cnt[tid];
  __syncthreads();
  for (int o = 1; o < BDST; o <<= 1) {
    int v = 0;
    if (tid < BDST && tid >= o) v = tmp[tid - o];
    __syncthreads();
    if (tid < BDST && tid >= o) tmp[tid] += v;
    __syncthreads();
  }
  if (tid < BDST) off[tid] = (tid == 0) ? 0 : tmp[tid - 1];
  __syncthreads();

  // rowp for this bucket's nodes
  if (tid < BDST) {
    const int node = bkt * BDST + tid;
    if (node < nDst) rowp[node] = rbeg + off[tid];
  }
  if (blockIdx.x == 0 && tid == 0) rowp_m[NM] = NE;
  if (blockIdx.x == BM_BKTS && tid == 0) rowp_u[NU] = NE;

  // reuse cnt as claim cursors
  if (tid < BDST) cnt[tid] = 0;
  __syncthreads();
  for (int j = rbeg + tid; j < rend; j += 256) {
    const int q = recs[j];
    const int dl = q & (BDST - 1);
    const int pos = atomicAdd(&cnt[dl], 1);
    adj[rbeg + off[dl] + pos] = q >> 7;
  }
}

// ---------------------------------------------------------------------------
// CSR gather-aggregate (wave per node, lane = feature). High occupancy.
// ---------------------------------------------------------------------------
__device__ __forceinline__ void agg_one(const float* __restrict__ xsrc,
                                        const int* __restrict__ rowp,
                                        const int* __restrict__ adj,
                                        float* __restrict__ mean_out,
                                        int node, int lane) {
  const int beg = rowp[node];
  const int end = rowp[node + 1];
  float acc = 0.f;
  int j = beg;
  for (; j + 8 <= end; j += 8) {
    const int s0 = adj[j],     s1 = adj[j + 1], s2 = adj[j + 2], s3 = adj[j + 3];
    const int s4 = adj[j + 4], s5 = adj[j + 5], s6 = adj[j + 6], s7 = adj[j + 7];
    const float v0 = xsrc[(size_t)s0 * D + lane];
    const float v1 = xsrc[(size_t)s1 * D + lane];
    const float v2 = xsrc[(size_t)s2 * D + lane];
    const float v3 = xsrc[(size_t)s3 * D + lane];
    const float v4 = xsrc[(size_t)s4 * D + lane];
    const float v5 = xsrc[(size_t)s5 * D + lane];
    const float v6 = xsrc[(size_t)s6 * D + lane];
    const float v7 = xsrc[(size_t)s7 * D + lane];
    acc += ((v0 + v1) + (v2 + v3)) + ((v4 + v5) + (v6 + v7));
  }
  for (; j < end; ++j) acc += xsrc[(size_t)adj[j] * D + lane];
  const float cnt = (float)(end - beg);
  mean_out[(size_t)node * D + lane] = acc / fmaxf(cnt, 1.0f);
}

__global__ __launch_bounds__(256) void csr_both_k(const float* __restrict__ xu,
                                                  const float* __restrict__ xm,
                                                  const int* __restrict__ rowp_u,
                                                  const int* __restrict__ rowp_m,
                                                  const int* __restrict__ adj_u,
                                                  const int* __restrict__ adj_m,
                                                  float* __restrict__ agg_u,
                                                  float* __restrict__ agg_m) {
  const int lane = threadIdx.x & 63;
  const int wid  = (blockIdx.x * blockDim.x + threadIdx.x) >> 6;
  const int W    = (gridDim.x * blockDim.x) >> 6;
  const int WM   = W / 3;
  if (wid < WM) {
    for (int node = wid; node < NM; node += WM)
      agg_one(xu, rowp_m, adj_m, agg_m, node, lane);
  } else {
    const int uw = wid - WM, UW = W - WM;
    for (int node = uw; node < NU; node += UW)
      agg_one(xm, rowp_u, adj_u, agg_u, node, lane);
  }
}

// ---------------------------------------------------------------------------
// per-node SAGE update, both relations in one launch.
// ---------------------------------------------------------------------------
__global__ __launch_bounds__(256) void node_both_k(
    const float* __restrict__ agg_u, const float* __restrict__ agg_m,
    const float* __restrict__ xu,    const float* __restrict__ xm,
    const float* __restrict__ Wl_mu, const float* __restrict__ b_mu,
    const float* __restrict__ Wr_mu,
    const float* __restrict__ Wl_um, const float* __restrict__ b_um,
    const float* __restrict__ Wr_um,
    float* __restrict__ out_u, float* __restrict__ out_m, int do_relu) {
  const int lane = threadIdx.x & 63;
  const int wid  = (blockIdx.x * blockDim.x + threadIdx.x) >> 6;
  const int W    = (gridDim.x * blockDim.x) >> 6;
  const int WM   = W / 3;

  const float *Wl, *Wr, *bias, *mean_in, *xdst;
  float* out;
  int n, w0, nw;
  if (wid < WM) {
    Wl = Wl_um; Wr = Wr_um; bias = b_um;
    mean_in = agg_m; xdst = xm; out = out_m; n = NM; w0 = wid; nw = WM;
  } else {
    Wl = Wl_mu; Wr = Wr_mu; bias = b_mu;
    mean_in = agg_u; xdst = xu; out = out_u; n = NU; w0 = wid - WM; nw = W - WM;
  }

  float wl[D], wr[D];
#pragma unroll
  for (int k = 0; k < D; ++k) {
    wl[k] = Wl[k * D + lane];
    wr[k] = Wr[k * D + lane];
  }
  const float b = bias[lane];

  for (int node = w0; node < n; node += nw) {
    const float mean = mean_in[(size_t)node * D + lane];
    const float xv   = xdst[(size_t)node * D + lane];

    float a0 = 0.f, a1 = 0.f, a2 = 0.f, a3 = 0.f;
#pragma unroll
    for (int k = 0; k < D; k += 2) {
      const float mk0 = __uint_as_float(__builtin_amdgcn_readlane(__float_as_uint(mean), k));
      const float xk0 = __uint_as_float(__builtin_amdgcn_readlane(__float_as_uint(xv),   k));
      const float mk1 = __uint_as_float(__builtin_amdgcn_readlane(__float_as_uint(mean), k + 1));
      const float xk1 = __uint_as_float(__builtin_amdgcn_readlane(__float_as_uint(xv),   k + 1));
      a0 = fmaf(mk0, wl[k],     a0);
      a1 = fmaf(xk0, wr[k],     a1);
      a2 = fmaf(mk1, wl[k + 1], a2);
      a3 = fmaf(xk1, wr[k + 1], a3);
    }
    float acc = b + a0 + a1 + a2 + a3;
    if (do_relu) acc = fmaxf(acc, 0.0f);
    out[(size_t)node * D + lane] = acc;
  }
}

// ---------------------------------------------------------------------------
extern "C" void kernel_launch(void* const* d_in, const int* in_sizes, int n_in,
                              void* d_out, int out_size, void* d_ws, size_t ws_size,
                              hipStream_t stream) {
  const float* x_user  = (const float*)d_in[0];
  const float* x_movie = (const float*)d_in[1];
  const float* Wl1_um = (const float*)d_in[2];
  const float* Wr1_um = (const float*)d_in[3];
  const float* b1_um  = (const float*)d_in[4];
  const float* Wl1_mu = (const float*)d_in[5];
  const float* Wr1_mu = (const float*)d_in[6];
  const float* b1_mu  = (const float*)d_in[7];
  const float* Wl2_um = (const float*)d_in[8];
  const float* Wr2_um = (const float*)d_in[9];
  const float* b2_um  = (const float*)d_in[10];
  const float* Wl2_mu = (const float*)d_in[11];
  const float* Wr2_mu = (const float*)d_in[12];
  const float* b2_mu  = (const float*)d_in[13];
  const int* uidx = (const int*)d_in[14];
  const int* midx = (const int*)d_in[15];

  // ---- workspace layout (aliasing: rec_* inside u1, C_* inside m1; both
  //      dead before u1/m1 are first written by node_both layer 1) ----
  char* ws = (char*)d_ws;
  float* u1    = (float*)ws;  ws += (size_t)NU * D * sizeof(float);   // 51.2 MB
  float* m1    = (float*)ws;  ws += (size_t)NM * D * sizeof(float);   // 25.6 MB
  float* agg_u = (float*)ws;  ws += (size_t)NU * D * sizeof(float);   // 51.2 MB
  float* agg_m = (float*)ws;  ws += (size_t)NM * D * sizeof(float);   // 25.6 MB
  int* rowp_u = (int*)ws;     ws += ((size_t)NU + 1) * sizeof(int);
  int* rowp_m = (int*)ws;     ws += ((size_t)NM + 1) * sizeof(int);
  int* adj_u  = (int*)ws;     ws += (size_t)NE * sizeof(int);         // 16 MB
  int* adj_m  = (int*)ws;     ws += (size_t)NE * sizeof(int);         // 16 MB
  int* tot_u  = (int*)ws;     ws += (size_t)BU_BKTS * sizeof(int);
  int* tot_m  = (int*)ws;     ws += (size_t)BM_BKTS * sizeof(int);
  int* bb_u   = (int*)ws;     ws += ((size_t)BU_BKTS + 1) * sizeof(int);
  int* bb_m   = (int*)ws;     ws += ((size_t)BM_BKTS + 1) * sizeof(int);

  int* rec_u = (int*)u1;                          // 16 MB \ inside u1
  int* rec_m = rec_u + NE;                        // 16 MB /
  int* C_u   = (int*)m1;                          // 6.4 MB \ inside m1
  int* C_m   = C_u + (size_t)NBLK * BU_BKTS;      // 3.2 MB /

  float* u2 = (float*)d_out;
  float* m2 = (float*)d_out + (size_t)NU * D;

  const dim3 blk(256);

  // ---- CSR build, zero global atomics (graph identical for both layers) ----
  hist_k<<<NBLK, blk, 0, stream>>>(uidx, midx, C_u, C_m);
  colscan_k<<<(NBKT + 255) / 256, blk, 0, stream>>>(C_u, C_m, tot_u, tot_m);
  bucketscan_k<<<1, 1024, 0, stream>>>(tot_u, bb_u, tot_m, bb_m);
  part_k<<<NBLK, blk, 0, stream>>>(uidx, midx, C_u, C_m, bb_u, bb_m, rec_u, rec_m);
  sort_k<<<NBKT, blk, 0, stream>>>(rec_m, rec_u, bb_m, bb_u,
                                   adj_m, adj_u, rowp_m, rowp_u);

  // ---- layer 1 (relu) ----
  csr_both_k<<<3072, blk, 0, stream>>>(x_user, x_movie, rowp_u, rowp_m,
                                       adj_u, adj_m, agg_u, agg_m);
  node_both_k<<<3072, blk, 0, stream>>>(agg_u, agg_m, x_user, x_movie,
                                        Wl1_mu, b1_mu, Wr1_mu,
                                        Wl1_um, b1_um, Wr1_um,
                                        u1, m1, 1);

  // ---- layer 2 (no activation, write d_out) ----
  csr_both_k<<<3072, blk, 0, stream>>>(u1, m1, rowp_u, rowp_m,
                                       adj_u, adj_m, agg_u, agg_m);
  node_both_k<<<3072, blk, 0, stream>>>(agg_u, agg_m, u1, m1,
                                        Wl2_mu, b2_mu, Wr2_mu,
                                        Wl2_um, b2_um, Wr2_um,
                                        u2, m2, 0);
}

// Round 7
// 938.839 us; speedup vs baseline: 6.1430x; 1.2362x over previous
//
#include <hip/hip_runtime.h>

#define NU 200000
#define NM 100000
#define NE 4000000
#define D  64

#define BDST 128                           // destinations per bucket (dst >> 7)
#define BU_BKTS ((NU + BDST - 1) / BDST)   // 1563 user buckets
#define BM_BKTS ((NM + BDST - 1) / BDST)   // 782 movie buckets
#define NBKT (BU_BKTS + BM_BKTS)           // 2345
#define NBLK 256                           // partition blocking
#define CHUNK ((NE + NBLK - 1) / NBLK)     // 15625

typedef unsigned int uint_t;
typedef unsigned short ushort_t;

__device__ __forceinline__ ushort_t f2bf(float f) {            // RNE f32->bf16
  uint_t u = __float_as_uint(f);
  return (ushort_t)((u + 0x7FFFu + ((u >> 16) & 1u)) >> 16);
}
__device__ __forceinline__ float bflo(uint_t p) { return __uint_as_float(p << 16); }
__device__ __forceinline__ float bfhi(uint_t p) { return __uint_as_float(p & 0xFFFF0000u); }

// ---------------------------------------------------------------------------
// cast x_user / x_movie to bf16 (vectorized float4 -> ushort4)
// ---------------------------------------------------------------------------
__global__ __launch_bounds__(256) void cast_k(const float* __restrict__ xu,
                                              const float* __restrict__ xm,
                                              ushort_t* __restrict__ xu_h,
                                              ushort_t* __restrict__ xm_h) {
  const int n_u = NU * D / 4, n_m = NM * D / 4;
  const int stride = gridDim.x * blockDim.x;
  for (int i = blockIdx.x * blockDim.x + threadIdx.x; i < n_u + n_m; i += stride) {
    const bool isu = (i < n_u);
    const float4 v = isu ? ((const float4*)xu)[i] : ((const float4*)xm)[i - n_u];
    ushort4 o;
    o.x = f2bf(v.x); o.y = f2bf(v.y); o.z = f2bf(v.z); o.w = f2bf(v.w);
    if (isu) ((ushort4*)xu_h)[i] = o;
    else     ((ushort4*)xm_h)[i - n_u] = o;
  }
}

// ---------------------------------------------------------------------------
// K1: per-block bucket histogram (both directions), LDS atomics only.
// ---------------------------------------------------------------------------
__global__ __launch_bounds__(256) void hist_k(const int* __restrict__ uidx,
                                              const int* __restrict__ midx,
                                              int* __restrict__ C_u,
                                              int* __restrict__ C_m) {
  __shared__ int h[NBKT];
  for (int i = threadIdx.x; i < NBKT; i += 256) h[i] = 0;
  __syncthreads();
  const int base = blockIdx.x * CHUNK;
  const int lim = min(base + CHUNK, NE);
  for (int e = base + threadIdx.x; e < lim; e += 256) {
    atomicAdd(&h[uidx[e] >> 7], 1);
    atomicAdd(&h[BU_BKTS + (midx[e] >> 7)], 1);
  }
  __syncthreads();
  for (int i = threadIdx.x; i < BU_BKTS; i += 256) C_u[(size_t)blockIdx.x * BU_BKTS + i] = h[i];
  for (int i = threadIdx.x; i < BM_BKTS; i += 256) C_m[(size_t)blockIdx.x * BM_BKTS + i] = h[BU_BKTS + i];
}

// ---------------------------------------------------------------------------
// K2a: per-bucket exclusive prefix over the 256 blocks; emit bucket totals.
// ---------------------------------------------------------------------------
__global__ __launch_bounds__(256) void colscan_k(int* __restrict__ C_u,
                                                 int* __restrict__ C_m,
                                                 int* __restrict__ tot_u,
                                                 int* __restrict__ tot_m) {
  const int t = blockIdx.x * blockDim.x + threadIdx.x;
  if (t < BU_BKTS) {
    int run = 0;
    for (int blk = 0; blk < NBLK; ++blk) {
      const size_t idx = (size_t)blk * BU_BKTS + t;
      const int v = C_u[idx];
      C_u[idx] = run;
      run += v;
    }
    tot_u[t] = run;
  } else if (t < NBKT) {
    const int b = t - BU_BKTS;
    int run = 0;
    for (int blk = 0; blk < NBLK; ++blk) {
      const size_t idx = (size_t)blk * BM_BKTS + b;
      const int v = C_m[idx];
      C_m[idx] = run;
      run += v;
    }
    tot_m[b] = run;
  }
}

// ---------------------------------------------------------------------------
// K2b: single-block exclusive scans of bucket totals -> bucket bases.
// ---------------------------------------------------------------------------
__device__ void scan_inline(const int* __restrict__ in, int* __restrict__ out,
                            int n, int* partial) {
  const int tid = threadIdx.x;
  const int chunk = (n + 1023) / 1024;
  const int s = tid * chunk;
  const int e = min(s + chunk, n);
  int sum = 0;
  for (int i = s; i < e; ++i) sum += in[i];
  partial[tid] = sum;
  __syncthreads();
  for (int off = 1; off < 1024; off <<= 1) {
    int v = (tid >= off) ? partial[tid - off] : 0;
    __syncthreads();
    if (tid >= off) partial[tid] += v;
    __syncthreads();
  }
  int run = (tid == 0) ? 0 : partial[tid - 1];
  for (int i = s; i < e; ++i) {
    out[i] = run;
    run += in[i];
  }
  if (tid == 1023) out[n] = partial[1023];
}

__global__ __launch_bounds__(1024) void bucketscan_k(const int* __restrict__ tot_u,
                                                     int* __restrict__ bb_u,
                                                     const int* __restrict__ tot_m,
                                                     int* __restrict__ bb_m) {
  __shared__ int partial[1024];
  scan_inline(tot_u, bb_u, BU_BKTS, partial);
  __syncthreads();
  scan_inline(tot_m, bb_m, BM_BKTS, partial);
}

// ---------------------------------------------------------------------------
// K3: partition pass, LDS cursors only. rec = (src << 7) | dstlow.
// ---------------------------------------------------------------------------
__global__ __launch_bounds__(256) void part_k(const int* __restrict__ uidx,
                                              const int* __restrict__ midx,
                                              const int* __restrict__ C_u,
                                              const int* __restrict__ C_m,
                                              const int* __restrict__ bb_u,
                                              const int* __restrict__ bb_m,
                                              int* __restrict__ rec_u,
                                              int* __restrict__ rec_m) {
  __shared__ int cur[NBKT];
  for (int i = threadIdx.x; i < BU_BKTS; i += 256)
    cur[i] = bb_u[i] + C_u[(size_t)blockIdx.x * BU_BKTS + i];
  for (int i = threadIdx.x; i < BM_BKTS; i += 256)
    cur[BU_BKTS + i] = bb_m[i] + C_m[(size_t)blockIdx.x * BM_BKTS + i];
  __syncthreads();
  const int base = blockIdx.x * CHUNK;
  const int lim = min(base + CHUNK, NE);
  for (int e = base + threadIdx.x; e < lim; e += 256) {
    const int u = uidx[e];
    const int m = midx[e];
    const int pu = atomicAdd(&cur[u >> 7], 1);
    rec_u[pu] = (m << 7) | (u & (BDST - 1));
    const int pm = atomicAdd(&cur[BU_BKTS + (m >> 7)], 1);
    rec_m[pm] = (u << 7) | (m & (BDST - 1));
  }
}

// ---------------------------------------------------------------------------
// K4: per-bucket counting sort -> per-node CSR (adj + rowp). LDS atomics only.
// ---------------------------------------------------------------------------
__global__ __launch_bounds__(256) void sort_k(const int* __restrict__ rec_m,
                                              const int* __restrict__ rec_u,
                                              const int* __restrict__ bb_m,
                                              const int* __restrict__ bb_u,
                                              int* __restrict__ adj_m,
                                              int* __restrict__ adj_u,
                                              int* __restrict__ rowp_m,
                                              int* __restrict__ rowp_u) {
  __shared__ int cnt[BDST];
  __shared__ int off[BDST];
  __shared__ int tmp[BDST];
  const bool is_m = (blockIdx.x < BM_BKTS);
  const int bkt = is_m ? blockIdx.x : blockIdx.x - BM_BKTS;
  const int* recs = is_m ? rec_m : rec_u;
  const int* bb   = is_m ? bb_m : bb_u;
  int* adj  = is_m ? adj_m : adj_u;
  int* rowp = is_m ? rowp_m : rowp_u;
  const int nDst = is_m ? NM : NU;
  const int tid = threadIdx.x;

  for (int i = tid; i < BDST; i += 256) cnt[i] = 0;
  __syncthreads();
  const int rbeg = bb[bkt], rend = bb[bkt + 1];
  for (int j = rbeg + tid; j < rend; j += 256)
    atomicAdd(&cnt[recs[j] & (BDST - 1)], 1);
  __syncthreads();

  if (tid < BDST) tmp[tid] = cnt[tid];
  __syncthreads();
  for (int o = 1; o < BDST; o <<= 1) {
    int v = 0;
    if (tid < BDST && tid >= o) v = tmp[tid - o];
    __syncthreads();
    if (tid < BDST && tid >= o) tmp[tid] += v;
    __syncthreads();
  }
  if (tid < BDST) off[tid] = (tid == 0) ? 0 : tmp[tid - 1];
  __syncthreads();

  if (tid < BDST) {
    const int node = bkt * BDST + tid;
    if (node < nDst) rowp[node] = rbeg + off[tid];
  }
  if (blockIdx.x == 0 && tid == 0) rowp_m[NM] = NE;
  if (blockIdx.x == BM_BKTS && tid == 0) rowp_u[NU] = NE;

  if (tid < BDST) cnt[tid] = 0;
  __syncthreads();
  for (int j = rbeg + tid; j < rend; j += 256) {
    const int q = recs[j];
    const int dl = q & (BDST - 1);
    const int pos = atomicAdd(&cnt[dl], 1);
    adj[rbeg + off[dl] + pos] = q >> 7;
  }
}

// ---------------------------------------------------------------------------
// bf16 CSR gather-aggregate: TWO rows per wave (lanes 0-31 edge j, lanes
// 32-63 edge j+1), each lane loads one uint = 2 bf16 features. f32 acc;
// halves combined via shfl_xor(32); mean written as coalesced float2.
// ---------------------------------------------------------------------------
__device__ __forceinline__ void agg_pair(const ushort_t* __restrict__ xh,
                                         const int* __restrict__ rowp,
                                         const int* __restrict__ adj,
                                         float* __restrict__ mean_out,
                                         int node, int half, int l32) {
  const uint_t* x32 = (const uint_t*)xh;
  const int beg = rowp[node];
  const int end = rowp[node + 1];
  float ax = 0.f, ay = 0.f;
  int j = beg;
  for (; j + 16 <= end; j += 16) {
    const int e0 = adj[j +      half], e1 = adj[j +  2 + half];
    const int e2 = adj[j +  4 + half], e3 = adj[j +  6 + half];
    const int e4 = adj[j +  8 + half], e5 = adj[j + 10 + half];
    const int e6 = adj[j + 12 + half], e7 = adj[j + 14 + half];
    const uint_t p0 = x32[(size_t)e0 * 32 + l32];
    const uint_t p1 = x32[(size_t)e1 * 32 + l32];
    const uint_t p2 = x32[(size_t)e2 * 32 + l32];
    const uint_t p3 = x32[(size_t)e3 * 32 + l32];
    const uint_t p4 = x32[(size_t)e4 * 32 + l32];
    const uint_t p5 = x32[(size_t)e5 * 32 + l32];
    const uint_t p6 = x32[(size_t)e6 * 32 + l32];
    const uint_t p7 = x32[(size_t)e7 * 32 + l32];
    ax += ((bflo(p0) + bflo(p1)) + (bflo(p2) + bflo(p3))) +
          ((bflo(p4) + bflo(p5)) + (bflo(p6) + bflo(p7)));
    ay += ((bfhi(p0) + bfhi(p1)) + (bfhi(p2) + bfhi(p3))) +
          ((bfhi(p4) + bfhi(p5)) + (bfhi(p6) + bfhi(p7)));
  }
  for (; j + 2 <= end; j += 2) {
    const uint_t p = x32[(size_t)adj[j + half] * 32 + l32];
    ax += bflo(p);
    ay += bfhi(p);
  }
  if (j < end && half == 0) {            // odd final edge: low half only
    const uint_t p = x32[(size_t)adj[j] * 32 + l32];
    ax += bflo(p);
    ay += bfhi(p);
  }
  const float ox = __shfl_xor(ax, 32);
  const float oy = __shfl_xor(ay, 32);
  const float inv = 1.0f / fmaxf((float)(end - beg), 1.0f);
  if (half == 0) {
    float2 r;
    r.x = (ax + ox) * inv;
    r.y = (ay + oy) * inv;
    *(float2*)&mean_out[(size_t)node * D + 2 * l32] = r;
  }
}

__global__ __launch_bounds__(256) void csr_both_h(const ushort_t* __restrict__ xu_h,
                                                  const ushort_t* __restrict__ xm_h,
                                                  const int* __restrict__ rowp_u,
                                                  const int* __restrict__ rowp_m,
                                                  const int* __restrict__ adj_u,
                                                  const int* __restrict__ adj_m,
                                                  float* __restrict__ agg_u,
                                                  float* __restrict__ agg_m) {
  const int lane = threadIdx.x & 63;
  const int half = lane >> 5;
  const int l32 = lane & 31;
  const int wid  = (blockIdx.x * blockDim.x + threadIdx.x) >> 6;
  const int W    = (gridDim.x * blockDim.x) >> 6;
  const int WM   = W / 3;
  if (wid < WM) {
    for (int node = wid; node < NM; node += WM)
      agg_pair(xu_h, rowp_m, adj_m, agg_m, node, half, l32);
  } else {
    const int uw = wid - WM, UW = W - WM;
    for (int node = uw; node < NU; node += UW)
      agg_pair(xm_h, rowp_u, adj_u, agg_u, node, half, l32);
  }
}

// ---------------------------------------------------------------------------
// per-node SAGE update, both relations. mode 1: layer1 (relu, xdst=f32,
// write bf16). mode 0: layer2 (xdst=bf16, write f32 d_out).
// ---------------------------------------------------------------------------
__global__ __launch_bounds__(256) void node_both_k(
    const float* __restrict__ agg_u, const float* __restrict__ agg_m,
    const float* __restrict__ xu_f,  const float* __restrict__ xm_f,
    const ushort_t* __restrict__ xu_h, const ushort_t* __restrict__ xm_h,
    const float* __restrict__ Wl_mu, const float* __restrict__ b_mu,
    const float* __restrict__ Wr_mu,
    const float* __restrict__ Wl_um, const float* __restrict__ b_um,
    const float* __restrict__ Wr_um,
    float* __restrict__ outf_u, float* __restrict__ outf_m,
    ushort_t* __restrict__ outh_u, ushort_t* __restrict__ outh_m, int mode) {
  const int lane = threadIdx.x & 63;
  const int wid  = (blockIdx.x * blockDim.x + threadIdx.x) >> 6;
  const int W    = (gridDim.x * blockDim.x) >> 6;
  const int WM   = W / 3;

  const float *Wl, *Wr, *bias, *mean_in, *xf;
  const ushort_t* xh;
  float* outf;
  ushort_t* outh;
  int n, w0, nw;
  if (wid < WM) {
    Wl = Wl_um; Wr = Wr_um; bias = b_um;
    mean_in = agg_m; xf = xm_f; xh = xm_h; outf = outf_m; outh = outh_m;
    n = NM; w0 = wid; nw = WM;
  } else {
    Wl = Wl_mu; Wr = Wr_mu; bias = b_mu;
    mean_in = agg_u; xf = xu_f; xh = xu_h; outf = outf_u; outh = outh_u;
    n = NU; w0 = wid - WM; nw = W - WM;
  }

  float wl[D], wr[D];
#pragma unroll
  for (int k = 0; k < D; ++k) {
    wl[k] = Wl[k * D + lane];
    wr[k] = Wr[k * D + lane];
  }
  const float b = bias[lane];

  for (int node = w0; node < n; node += nw) {
    const float mean = mean_in[(size_t)node * D + lane];
    const float xv = mode ? xf[(size_t)node * D + lane]
                          : __uint_as_float((uint_t)xh[(size_t)node * D + lane] << 16);

    float a0 = 0.f, a1 = 0.f, a2 = 0.f, a3 = 0.f;
#pragma unroll
    for (int k = 0; k < D; k += 2) {
      const float mk0 = __uint_as_float(__builtin_amdgcn_readlane(__float_as_uint(mean), k));
      const float xk0 = __uint_as_float(__builtin_amdgcn_readlane(__float_as_uint(xv),   k));
      const float mk1 = __uint_as_float(__builtin_amdgcn_readlane(__float_as_uint(mean), k + 1));
      const float xk1 = __uint_as_float(__builtin_amdgcn_readlane(__float_as_uint(xv),   k + 1));
      a0 = fmaf(mk0, wl[k],     a0);
      a1 = fmaf(xk0, wr[k],     a1);
      a2 = fmaf(mk1, wl[k + 1], a2);
      a3 = fmaf(xk1, wr[k + 1], a3);
    }
    float acc = b + a0 + a1 + a2 + a3;
    if (mode) {
      acc = fmaxf(acc, 0.0f);
      outh[(size_t)node * D + lane] = f2bf(acc);
    } else {
      outf[(size_t)node * D + lane] = acc;
    }
  }
}

// ---------------------------------------------------------------------------
extern "C" void kernel_launch(void* const* d_in, const int* in_sizes, int n_in,
                              void* d_out, int out_size, void* d_ws, size_t ws_size,
                              hipStream_t stream) {
  const float* x_user  = (const float*)d_in[0];
  const float* x_movie = (const float*)d_in[1];
  const float* Wl1_um = (const float*)d_in[2];
  const float* Wr1_um = (const float*)d_in[3];
  const float* b1_um  = (const float*)d_in[4];
  const float* Wl1_mu = (const float*)d_in[5];
  const float* Wr1_mu = (const float*)d_in[6];
  const float* b1_mu  = (const float*)d_in[7];
  const float* Wl2_um = (const float*)d_in[8];
  const float* Wr2_um = (const float*)d_in[9];
  const float* b2_um  = (const float*)d_in[10];
  const float* Wl2_mu = (const float*)d_in[11];
  const float* Wr2_mu = (const float*)d_in[12];
  const float* b2_mu  = (const float*)d_in[13];
  const int* uidx = (const int*)d_in[14];
  const int* midx = (const int*)d_in[15];

  // ---- workspace layout (aliasing: rec_* inside agg_u, C_* inside agg_m;
  //      both dead before agg_* are first written by csr_both layer 1) ----
  char* ws = (char*)d_ws;
  float* agg_u = (float*)ws;    ws += (size_t)NU * D * sizeof(float);     // 51.2 MB
  float* agg_m = (float*)ws;    ws += (size_t)NM * D * sizeof(float);     // 25.6 MB
  ushort_t* xu_h = (ushort_t*)ws; ws += (size_t)NU * D * sizeof(ushort_t); // 25.6 MB
  ushort_t* xm_h = (ushort_t*)ws; ws += (size_t)NM * D * sizeof(ushort_t); // 12.8 MB
  ushort_t* u1_h = (ushort_t*)ws; ws += (size_t)NU * D * sizeof(ushort_t); // 25.6 MB
  ushort_t* m1_h = (ushort_t*)ws; ws += (size_t)NM * D * sizeof(ushort_t); // 12.8 MB
  int* adj_u  = (int*)ws;       ws += (size_t)NE * sizeof(int);           // 16 MB
  int* adj_m  = (int*)ws;       ws += (size_t)NE * sizeof(int);           // 16 MB
  int* rowp_u = (int*)ws;       ws += ((size_t)NU + 1) * sizeof(int);
  int* rowp_m = (int*)ws;       ws += ((size_t)NM + 1) * sizeof(int);
  int* tot_u  = (int*)ws;       ws += (size_t)BU_BKTS * sizeof(int);
  int* tot_m  = (int*)ws;       ws += (size_t)BM_BKTS * sizeof(int);
  int* bb_u   = (int*)ws;       ws += ((size_t)BU_BKTS + 1) * sizeof(int);
  int* bb_m   = (int*)ws;       ws += ((size_t)BM_BKTS + 1) * sizeof(int);

  int* rec_u = (int*)agg_u;                       // 16 MB \ inside agg_u
  int* rec_m = rec_u + NE;                        // 16 MB /
  int* C_u   = (int*)agg_m;                       // 1.6 MB \ inside agg_m
  int* C_m   = C_u + (size_t)NBLK * BU_BKTS;      // 0.8 MB /

  float* u2 = (float*)d_out;
  float* m2 = (float*)d_out + (size_t)NU * D;

  const dim3 blk(256);

  // ---- bf16 casts + CSR build (graph identical for both layers) ----
  cast_k<<<2048, blk, 0, stream>>>(x_user, x_movie, xu_h, xm_h);
  hist_k<<<NBLK, blk, 0, stream>>>(uidx, midx, C_u, C_m);
  colscan_k<<<(NBKT + 255) / 256, blk, 0, stream>>>(C_u, C_m, tot_u, tot_m);
  bucketscan_k<<<1, 1024, 0, stream>>>(tot_u, bb_u, tot_m, bb_m);
  part_k<<<NBLK, blk, 0, stream>>>(uidx, midx, C_u, C_m, bb_u, bb_m, rec_u, rec_m);
  sort_k<<<NBKT, blk, 0, stream>>>(rec_m, rec_u, bb_m, bb_u,
                                   adj_m, adj_u, rowp_m, rowp_u);

  // ---- layer 1 (relu, outputs bf16 u1_h/m1_h) ----
  csr_both_h<<<3072, blk, 0, stream>>>(xu_h, xm_h, rowp_u, rowp_m,
                                       adj_u, adj_m, agg_u, agg_m);
  node_both_k<<<3072, blk, 0, stream>>>(agg_u, agg_m, x_user, x_movie, xu_h, xm_h,
                                        Wl1_mu, b1_mu, Wr1_mu,
                                        Wl1_um, b1_um, Wr1_um,
                                        nullptr, nullptr, u1_h, m1_h, 1);

  // ---- layer 2 (no activation, writes f32 d_out) ----
  csr_both_h<<<3072, blk, 0, stream>>>(u1_h, m1_h, rowp_u, rowp_m,
                                       adj_u, adj_m, agg_u, agg_m);
  node_both_k<<<3072, blk, 0, stream>>>(agg_u, agg_m, nullptr, nullptr, u1_h, m1_h,
                                        Wl2_mu, b2_mu, Wr2_mu,
                                        Wl2_um, b2_um, Wr2_um,
                                        u2, m2, nullptr, nullptr, 0);
}

// Round 8
// 856.874 us; speedup vs baseline: 6.7306x; 1.0957x over previous
//
#include <hip/hip_runtime.h>

#define NU 200000
#define NM 100000
#define NE 4000000
#define D  64

#define BDST 128                           // destinations per bucket (dst >> 7)
#define BU_BKTS ((NU + BDST - 1) / BDST)   // 1563 user buckets
#define BM_BKTS ((NM + BDST - 1) / BDST)   // 782 movie buckets
#define NBKT (BU_BKTS + BM_BKTS)           // 2345
#define NBLK 256                           // partition blocking
#define CHUNK ((NE + NBLK - 1) / NBLK)     // 15625

typedef unsigned int uint_t;
typedef unsigned short ushort_t;

__device__ __forceinline__ ushort_t f2bf(float f) {            // RNE f32->bf16
  uint_t u = __float_as_uint(f);
  return (ushort_t)((u + 0x7FFFu + ((u >> 16) & 1u)) >> 16);
}
__device__ __forceinline__ float bflo(uint_t p) { return __uint_as_float(p << 16); }
__device__ __forceinline__ float bfhi(uint_t p) { return __uint_as_float(p & 0xFFFF0000u); }

// ---------------------------------------------------------------------------
// cast x_user / x_movie to bf16 (vectorized float4 -> ushort4)
// ---------------------------------------------------------------------------
__global__ __launch_bounds__(256) void cast_k(const float* __restrict__ xu,
                                              const float* __restrict__ xm,
                                              ushort_t* __restrict__ xu_h,
                                              ushort_t* __restrict__ xm_h) {
  const int n_u = NU * D / 4, n_m = NM * D / 4;
  const int stride = gridDim.x * blockDim.x;
  for (int i = blockIdx.x * blockDim.x + threadIdx.x; i < n_u + n_m; i += stride) {
    const bool isu = (i < n_u);
    const float4 v = isu ? ((const float4*)xu)[i] : ((const float4*)xm)[i - n_u];
    ushort4 o;
    o.x = f2bf(v.x); o.y = f2bf(v.y); o.z = f2bf(v.z); o.w = f2bf(v.w);
    if (isu) ((ushort4*)xu_h)[i] = o;
    else     ((ushort4*)xm_h)[i - n_u] = o;
  }
}

// ---------------------------------------------------------------------------
// K1: per-block bucket histogram (both directions), LDS atomics only.
// ---------------------------------------------------------------------------
__global__ __launch_bounds__(256) void hist_k(const int* __restrict__ uidx,
                                              const int* __restrict__ midx,
                                              int* __restrict__ C_u,
                                              int* __restrict__ C_m) {
  __shared__ int h[NBKT];
  for (int i = threadIdx.x; i < NBKT; i += 256) h[i] = 0;
  __syncthreads();
  const int base = blockIdx.x * CHUNK;
  const int lim = min(base + CHUNK, NE);
  for (int e = base + threadIdx.x; e < lim; e += 256) {
    atomicAdd(&h[uidx[e] >> 7], 1);
    atomicAdd(&h[BU_BKTS + (midx[e] >> 7)], 1);
  }
  __syncthreads();
  for (int i = threadIdx.x; i < BU_BKTS; i += 256) C_u[(size_t)blockIdx.x * BU_BKTS + i] = h[i];
  for (int i = threadIdx.x; i < BM_BKTS; i += 256) C_m[(size_t)blockIdx.x * BM_BKTS + i] = h[BU_BKTS + i];
}

// ---------------------------------------------------------------------------
// K2a: per-bucket exclusive prefix over the 256 blocks; emit bucket totals.
// ---------------------------------------------------------------------------
__global__ __launch_bounds__(256) void colscan_k(int* __restrict__ C_u,
                                                 int* __restrict__ C_m,
                                                 int* __restrict__ tot_u,
                                                 int* __restrict__ tot_m) {
  const int t = blockIdx.x * blockDim.x + threadIdx.x;
  if (t < BU_BKTS) {
    int run = 0;
    for (int blk = 0; blk < NBLK; ++blk) {
      const size_t idx = (size_t)blk * BU_BKTS + t;
      const int v = C_u[idx];
      C_u[idx] = run;
      run += v;
    }
    tot_u[t] = run;
  } else if (t < NBKT) {
    const int b = t - BU_BKTS;
    int run = 0;
    for (int blk = 0; blk < NBLK; ++blk) {
      const size_t idx = (size_t)blk * BM_BKTS + b;
      const int v = C_m[idx];
      C_m[idx] = run;
      run += v;
    }
    tot_m[b] = run;
  }
}

// ---------------------------------------------------------------------------
// K2b: single-block exclusive scans of bucket totals -> bucket bases.
// ---------------------------------------------------------------------------
__device__ void scan_inline(const int* __restrict__ in, int* __restrict__ out,
                            int n, int* partial) {
  const int tid = threadIdx.x;
  const int chunk = (n + 1023) / 1024;
  const int s = tid * chunk;
  const int e = min(s + chunk, n);
  int sum = 0;
  for (int i = s; i < e; ++i) sum += in[i];
  partial[tid] = sum;
  __syncthreads();
  for (int off = 1; off < 1024; off <<= 1) {
    int v = (tid >= off) ? partial[tid - off] : 0;
    __syncthreads();
    if (tid >= off) partial[tid] += v;
    __syncthreads();
  }
  int run = (tid == 0) ? 0 : partial[tid - 1];
  for (int i = s; i < e; ++i) {
    out[i] = run;
    run += in[i];
  }
  if (tid == 1023) out[n] = partial[1023];
}

__global__ __launch_bounds__(1024) void bucketscan_k(const int* __restrict__ tot_u,
                                                     int* __restrict__ bb_u,
                                                     const int* __restrict__ tot_m,
                                                     int* __restrict__ bb_m) {
  __shared__ int partial[1024];
  scan_inline(tot_u, bb_u, BU_BKTS, partial);
  __syncthreads();
  scan_inline(tot_m, bb_m, BM_BKTS, partial);
}

// ---------------------------------------------------------------------------
// K3: partition pass, LDS cursors only. rec = (src << 7) | dstlow.
// ---------------------------------------------------------------------------
__global__ __launch_bounds__(256) void part_k(const int* __restrict__ uidx,
                                              const int* __restrict__ midx,
                                              const int* __restrict__ C_u,
                                              const int* __restrict__ C_m,
                                              const int* __restrict__ bb_u,
                                              const int* __restrict__ bb_m,
                                              int* __restrict__ rec_u,
                                              int* __restrict__ rec_m) {
  __shared__ int cur[NBKT];
  for (int i = threadIdx.x; i < BU_BKTS; i += 256)
    cur[i] = bb_u[i] + C_u[(size_t)blockIdx.x * BU_BKTS + i];
  for (int i = threadIdx.x; i < BM_BKTS; i += 256)
    cur[BU_BKTS + i] = bb_m[i] + C_m[(size_t)blockIdx.x * BM_BKTS + i];
  __syncthreads();
  const int base = blockIdx.x * CHUNK;
  const int lim = min(base + CHUNK, NE);
  for (int e = base + threadIdx.x; e < lim; e += 256) {
    const int u = uidx[e];
    const int m = midx[e];
    const int pu = atomicAdd(&cur[u >> 7], 1);
    rec_u[pu] = (m << 7) | (u & (BDST - 1));
    const int pm = atomicAdd(&cur[BU_BKTS + (m >> 7)], 1);
    rec_m[pm] = (u << 7) | (m & (BDST - 1));
  }
}

// ---------------------------------------------------------------------------
// K4: per-bucket counting sort -> per-node CSR (adj + rowp). LDS atomics only.
// ---------------------------------------------------------------------------
__global__ __launch_bounds__(256) void sort_k(const int* __restrict__ rec_m,
                                              const int* __restrict__ rec_u,
                                              const int* __restrict__ bb_m,
                                              const int* __restrict__ bb_u,
                                              int* __restrict__ adj_m,
                                              int* __restrict__ adj_u,
                                              int* __restrict__ rowp_m,
                                              int* __restrict__ rowp_u) {
  __shared__ int cnt[BDST];
  __shared__ int off[BDST];
  __shared__ int tmp[BDST];
  const bool is_m = (blockIdx.x < BM_BKTS);
  const int bkt = is_m ? blockIdx.x : blockIdx.x - BM_BKTS;
  const int* recs = is_m ? rec_m : rec_u;
  const int* bb   = is_m ? bb_m : bb_u;
  int* adj  = is_m ? adj_m : adj_u;
  int* rowp = is_m ? rowp_m : rowp_u;
  const int nDst = is_m ? NM : NU;
  const int tid = threadIdx.x;

  for (int i = tid; i < BDST; i += 256) cnt[i] = 0;
  __syncthreads();
  const int rbeg = bb[bkt], rend = bb[bkt + 1];
  for (int j = rbeg + tid; j < rend; j += 256)
    atomicAdd(&cnt[recs[j] & (BDST - 1)], 1);
  __syncthreads();

  if (tid < BDST) tmp[tid] = cnt[tid];
  __syncthreads();
  for (int o = 1; o < BDST; o <<= 1) {
    int v = 0;
    if (tid < BDST && tid >= o) v = tmp[tid - o];
    __syncthreads();
    if (tid < BDST && tid >= o) tmp[tid] += v;
    __syncthreads();
  }
  if (tid < BDST) off[tid] = (tid == 0) ? 0 : tmp[tid - 1];
  __syncthreads();

  if (tid < BDST) {
    const int node = bkt * BDST + tid;
    if (node < nDst) rowp[node] = rbeg + off[tid];
  }
  if (blockIdx.x == 0 && tid == 0) rowp_m[NM] = NE;
  if (blockIdx.x == BM_BKTS && tid == 0) rowp_u[NU] = NE;

  if (tid < BDST) cnt[tid] = 0;
  __syncthreads();
  for (int j = rbeg + tid; j < rend; j += 256) {
    const int q = recs[j];
    const int dl = q & (BDST - 1);
    const int pos = atomicAdd(&cnt[dl], 1);
    adj[rbeg + off[dl] + pos] = q >> 7;
  }
}

// ---------------------------------------------------------------------------
// bf16 CSR gather-aggregate, uint2 edition: 16 lanes per edge-row (8 B/lane),
// one wave-load instruction covers 4 edge rows; 16 edges in flight per iter.
// Reduce across the 4 edge-groups with shfl_xor(16/32); mean stored bf16.
// ---------------------------------------------------------------------------
__device__ __forceinline__ void agg_node16(const uint2* __restrict__ x2,
                                           const int* __restrict__ rowp,
                                           const int* __restrict__ adj,
                                           uint2* __restrict__ mean_h2,
                                           int node, int g, int q) {
  const int beg = rowp[node];
  const int end = rowp[node + 1];
  float a0 = 0.f, a1 = 0.f, a2 = 0.f, a3 = 0.f;
  int j = beg;
  for (; j + 16 <= end; j += 16) {
    const int e0 = adj[j + g];
    const int e1 = adj[j + 4 + g];
    const int e2 = adj[j + 8 + g];
    const int e3 = adj[j + 12 + g];
    const uint2 p0 = x2[(size_t)e0 * 16 + q];
    const uint2 p1 = x2[(size_t)e1 * 16 + q];
    const uint2 p2 = x2[(size_t)e2 * 16 + q];
    const uint2 p3 = x2[(size_t)e3 * 16 + q];
    a0 += (bflo(p0.x) + bflo(p1.x)) + (bflo(p2.x) + bflo(p3.x));
    a1 += (bfhi(p0.x) + bfhi(p1.x)) + (bfhi(p2.x) + bfhi(p3.x));
    a2 += (bflo(p0.y) + bflo(p1.y)) + (bflo(p2.y) + bflo(p3.y));
    a3 += (bfhi(p0.y) + bfhi(p1.y)) + (bfhi(p2.y) + bfhi(p3.y));
  }
  for (; j + 4 <= end; j += 4) {
    const int e = adj[j + g];
    const uint2 p = x2[(size_t)e * 16 + q];
    a0 += bflo(p.x); a1 += bfhi(p.x); a2 += bflo(p.y); a3 += bfhi(p.y);
  }
  if (j < end && g < end - j) {          // remainder 1..3 edges
    const int e = adj[j + g];
    const uint2 p = x2[(size_t)e * 16 + q];
    a0 += bflo(p.x); a1 += bfhi(p.x); a2 += bflo(p.y); a3 += bfhi(p.y);
  }
  // combine the 4 edge-groups (lane bits 4,5)
  a0 += __shfl_xor(a0, 16); a1 += __shfl_xor(a1, 16);
  a2 += __shfl_xor(a2, 16); a3 += __shfl_xor(a3, 16);
  a0 += __shfl_xor(a0, 32); a1 += __shfl_xor(a1, 32);
  a2 += __shfl_xor(a2, 32); a3 += __shfl_xor(a3, 32);
  if (g == 0) {
    const float inv = 1.0f / fmaxf((float)(end - beg), 1.0f);
    uint2 o;
    o.x = (uint_t)f2bf(a0 * inv) | ((uint_t)f2bf(a1 * inv) << 16);
    o.y = (uint_t)f2bf(a2 * inv) | ((uint_t)f2bf(a3 * inv) << 16);
    mean_h2[(size_t)node * 16 + q] = o;
  }
}

__global__ __launch_bounds__(256) void csr_both_h(const uint2* __restrict__ xu2,
                                                  const uint2* __restrict__ xm2,
                                                  const int* __restrict__ rowp_u,
                                                  const int* __restrict__ rowp_m,
                                                  const int* __restrict__ adj_u,
                                                  const int* __restrict__ adj_m,
                                                  uint2* __restrict__ mean_u2,
                                                  uint2* __restrict__ mean_m2) {
  const int lane = threadIdx.x & 63;
  const int g = lane >> 4;              // edge group 0..3
  const int q = lane & 15;              // uint2 position within row
  const int wid  = (blockIdx.x * blockDim.x + threadIdx.x) >> 6;
  const int W    = (gridDim.x * blockDim.x) >> 6;
  const int WM   = W / 3;
  if (wid < WM) {
    for (int node = wid; node < NM; node += WM)
      agg_node16(xu2, rowp_m, adj_m, mean_m2, node, g, q);
  } else {
    const int uw = wid - WM, UW = W - WM;
    for (int node = uw; node < NU; node += UW)
      agg_node16(xm2, rowp_u, adj_u, mean_u2, node, g, q);
  }
}

// ---------------------------------------------------------------------------
// per-node SAGE update, both relations. mean and xdst both bf16.
// mode 1: relu + bf16 output; mode 0: f32 output (d_out).
// ---------------------------------------------------------------------------
__global__ __launch_bounds__(256) void node_both_k(
    const ushort_t* __restrict__ mean_u, const ushort_t* __restrict__ mean_m,
    const ushort_t* __restrict__ xu_h,   const ushort_t* __restrict__ xm_h,
    const float* __restrict__ Wl_mu, const float* __restrict__ b_mu,
    const float* __restrict__ Wr_mu,
    const float* __restrict__ Wl_um, const float* __restrict__ b_um,
    const float* __restrict__ Wr_um,
    float* __restrict__ outf_u, float* __restrict__ outf_m,
    ushort_t* __restrict__ outh_u, ushort_t* __restrict__ outh_m, int mode) {
  const int lane = threadIdx.x & 63;
  const int wid  = (blockIdx.x * blockDim.x + threadIdx.x) >> 6;
  const int W    = (gridDim.x * blockDim.x) >> 6;
  const int WM   = W / 3;

  const float *Wl, *Wr, *bias;
  const ushort_t *mean_in, *xh;
  float* outf;
  ushort_t* outh;
  int n, w0, nw;
  if (wid < WM) {
    Wl = Wl_um; Wr = Wr_um; bias = b_um;
    mean_in = mean_m; xh = xm_h; outf = outf_m; outh = outh_m;
    n = NM; w0 = wid; nw = WM;
  } else {
    Wl = Wl_mu; Wr = Wr_mu; bias = b_mu;
    mean_in = mean_u; xh = xu_h; outf = outf_u; outh = outh_u;
    n = NU; w0 = wid - WM; nw = W - WM;
  }

  float wl[D], wr[D];
#pragma unroll
  for (int k = 0; k < D; ++k) {
    wl[k] = Wl[k * D + lane];
    wr[k] = Wr[k * D + lane];
  }
  const float b = bias[lane];

  for (int node = w0; node < n; node += nw) {
    const float mean = __uint_as_float((uint_t)mean_in[(size_t)node * D + lane] << 16);
    const float xv   = __uint_as_float((uint_t)xh[(size_t)node * D + lane] << 16);

    float a0 = 0.f, a1 = 0.f, a2 = 0.f, a3 = 0.f;
#pragma unroll
    for (int k = 0; k < D; k += 2) {
      const float mk0 = __uint_as_float(__builtin_amdgcn_readlane(__float_as_uint(mean), k));
      const float xk0 = __uint_as_float(__builtin_amdgcn_readlane(__float_as_uint(xv),   k));
      const float mk1 = __uint_as_float(__builtin_amdgcn_readlane(__float_as_uint(mean), k + 1));
      const float xk1 = __uint_as_float(__builtin_amdgcn_readlane(__float_as_uint(xv),   k + 1));
      a0 = fmaf(mk0, wl[k],     a0);
      a1 = fmaf(xk0, wr[k],     a1);
      a2 = fmaf(mk1, wl[k + 1], a2);
      a3 = fmaf(xk1, wr[k + 1], a3);
    }
    float acc = b + a0 + a1 + a2 + a3;
    if (mode) {
      acc = fmaxf(acc, 0.0f);
      outh[(size_t)node * D + lane] = f2bf(acc);
    } else {
      outf[(size_t)node * D + lane] = acc;
    }
  }
}

// ---------------------------------------------------------------------------
extern "C" void kernel_launch(void* const* d_in, const int* in_sizes, int n_in,
                              void* d_out, int out_size, void* d_ws, size_t ws_size,
                              hipStream_t stream) {
  const float* x_user  = (const float*)d_in[0];
  const float* x_movie = (const float*)d_in[1];
  const float* Wl1_um = (const float*)d_in[2];
  const float* Wr1_um = (const float*)d_in[3];
  const float* b1_um  = (const float*)d_in[4];
  const float* Wl1_mu = (const float*)d_in[5];
  const float* Wr1_mu = (const float*)d_in[6];
  const float* b1_mu  = (const float*)d_in[7];
  const float* Wl2_um = (const float*)d_in[8];
  const float* Wr2_um = (const float*)d_in[9];
  const float* b2_um  = (const float*)d_in[10];
  const float* Wl2_mu = (const float*)d_in[11];
  const float* Wr2_mu = (const float*)d_in[12];
  const float* b2_mu  = (const float*)d_in[13];
  const int* uidx = (const int*)d_in[14];
  const int* midx = (const int*)d_in[15];

  // ---- workspace layout. Aliasing:
  //   rec_* (32 MB, dead after sort_k)  -> inside u1_h+m1_h (38.4 MB, first
  //                                        written by layer-1 node_both)
  //   C_*   (2.4 MB, dead after part_k) -> inside mean_u (25.6 MB, first
  //                                        written by layer-1 csr_both)
  char* ws = (char*)d_ws;
  ushort_t* mean_u = (ushort_t*)ws; ws += (size_t)NU * D * sizeof(ushort_t); // 25.6 MB
  ushort_t* mean_m = (ushort_t*)ws; ws += (size_t)NM * D * sizeof(ushort_t); // 12.8 MB
  ushort_t* xu_h = (ushort_t*)ws;   ws += (size_t)NU * D * sizeof(ushort_t); // 25.6 MB
  ushort_t* xm_h = (ushort_t*)ws;   ws += (size_t)NM * D * sizeof(ushort_t); // 12.8 MB
  ushort_t* u1_h = (ushort_t*)ws;   ws += (size_t)NU * D * sizeof(ushort_t); // 25.6 MB
  ushort_t* m1_h = (ushort_t*)ws;   ws += (size_t)NM * D * sizeof(ushort_t); // 12.8 MB
  int* adj_u  = (int*)ws;           ws += (size_t)NE * sizeof(int);          // 16 MB
  int* adj_m  = (int*)ws;           ws += (size_t)NE * sizeof(int);          // 16 MB
  int* rowp_u = (int*)ws;           ws += ((size_t)NU + 1) * sizeof(int);
  int* rowp_m = (int*)ws;           ws += ((size_t)NM + 1) * sizeof(int);
  int* tot_u  = (int*)ws;           ws += (size_t)BU_BKTS * sizeof(int);
  int* tot_m  = (int*)ws;           ws += (size_t)BM_BKTS * sizeof(int);
  int* bb_u   = (int*)ws;           ws += ((size_t)BU_BKTS + 1) * sizeof(int);
  int* bb_m   = (int*)ws;           ws += ((size_t)BM_BKTS + 1) * sizeof(int);

  int* rec_u = (int*)u1_h;                        // 16 MB \ inside u1_h+m1_h
  int* rec_m = rec_u + NE;                        // 16 MB /
  int* C_u   = (int*)mean_u;                      // 1.6 MB \ inside mean_u
  int* C_m   = C_u + (size_t)NBLK * BU_BKTS;      // 0.8 MB /

  float* u2 = (float*)d_out;
  float* m2 = (float*)d_out + (size_t)NU * D;

  const dim3 blk(256);

  // ---- bf16 casts + CSR build (graph identical for both layers) ----
  cast_k<<<2048, blk, 0, stream>>>(x_user, x_movie, xu_h, xm_h);
  hist_k<<<NBLK, blk, 0, stream>>>(uidx, midx, C_u, C_m);
  colscan_k<<<(NBKT + 255) / 256, blk, 0, stream>>>(C_u, C_m, tot_u, tot_m);
  bucketscan_k<<<1, 1024, 0, stream>>>(tot_u, bb_u, tot_m, bb_m);
  part_k<<<NBLK, blk, 0, stream>>>(uidx, midx, C_u, C_m, bb_u, bb_m, rec_u, rec_m);
  sort_k<<<NBKT, blk, 0, stream>>>(rec_m, rec_u, bb_m, bb_u,
                                   adj_m, adj_u, rowp_m, rowp_u);

  // ---- layer 1 (relu, outputs bf16 u1_h/m1_h) ----
  csr_both_h<<<3072, blk, 0, stream>>>((const uint2*)xu_h, (const uint2*)xm_h,
                                       rowp_u, rowp_m, adj_u, adj_m,
                                       (uint2*)mean_u, (uint2*)mean_m);
  node_both_k<<<3072, blk, 0, stream>>>(mean_u, mean_m, xu_h, xm_h,
                                        Wl1_mu, b1_mu, Wr1_mu,
                                        Wl1_um, b1_um, Wr1_um,
                                        nullptr, nullptr, u1_h, m1_h, 1);

  // ---- layer 2 (no activation, writes f32 d_out) ----
  csr_both_h<<<3072, blk, 0, stream>>>((const uint2*)u1_h, (const uint2*)m1_h,
                                       rowp_u, rowp_m, adj_u, adj_m,
                                       (uint2*)mean_u, (uint2*)mean_m);
  node_both_k<<<3072, blk, 0, stream>>>(mean_u, mean_m, u1_h, m1_h,
                                        Wl2_mu, b2_mu, Wr2_mu,
                                        Wl2_um, b2_um, Wr2_um,
                                        u2, m2, nullptr, nullptr, 0);
}

// Round 9
// 610.066 us; speedup vs baseline: 9.4535x; 1.4046x over previous
//
#include <hip/hip_runtime.h>

#define NU 200000
#define NM 100000
#define NE 4000000
#define D  64

#define BDST 128                           // destinations per bucket (dst >> 7)
#define BU_BKTS ((NU + BDST - 1) / BDST)   // 1563 user buckets
#define BM_BKTS ((NM + BDST - 1) / BDST)   // 782 movie buckets
#define NBKT (BU_BKTS + BM_BKTS)           // 2345
#define NBLK 256                           // partition blocking
#define CHUNK ((NE + NBLK - 1) / NBLK)     // 15625

typedef unsigned int uint_t;
typedef unsigned short ushort_t;
typedef __attribute__((ext_vector_type(8))) short short8_t;   // 8 bf16 (4 VGPR)
typedef __attribute__((ext_vector_type(4))) float f32x4_t;    // MFMA acc

__device__ __forceinline__ ushort_t f2bf(float f) {            // RNE f32->bf16
  uint_t u = __float_as_uint(f);
  return (ushort_t)((u + 0x7FFFu + ((u >> 16) & 1u)) >> 16);
}
__device__ __forceinline__ float bflo(uint_t p) { return __uint_as_float(p << 16); }
__device__ __forceinline__ float bfhi(uint_t p) { return __uint_as_float(p & 0xFFFF0000u); }

// ---------------------------------------------------------------------------
// cast x_user / x_movie to bf16 (vectorized float4 -> ushort4)
// ---------------------------------------------------------------------------
__global__ __launch_bounds__(256) void cast_k(const float* __restrict__ xu,
                                              const float* __restrict__ xm,
                                              ushort_t* __restrict__ xu_h,
                                              ushort_t* __restrict__ xm_h) {
  const int n_u = NU * D / 4, n_m = NM * D / 4;
  const int stride = gridDim.x * blockDim.x;
  for (int i = blockIdx.x * blockDim.x + threadIdx.x; i < n_u + n_m; i += stride) {
    const bool isu = (i < n_u);
    const float4 v = isu ? ((const float4*)xu)[i] : ((const float4*)xm)[i - n_u];
    ushort4 o;
    o.x = f2bf(v.x); o.y = f2bf(v.y); o.z = f2bf(v.z); o.w = f2bf(v.w);
    if (isu) ((ushort4*)xu_h)[i] = o;
    else     ((ushort4*)xm_h)[i - n_u] = o;
  }
}

// ---------------------------------------------------------------------------
// weight prep: swizzle 8 f32 64x64 matrices into per-lane MFMA B-fragments.
// frag[mat][t][h][lane][j] = bf16( W[h*32 + (lane>>4)*8 + j][t*16 + (lane&15)] )
// ---------------------------------------------------------------------------
__global__ __launch_bounds__(256) void wprep_k(
    const float* __restrict__ W0, const float* __restrict__ W1,
    const float* __restrict__ W2, const float* __restrict__ W3,
    const float* __restrict__ W4, const float* __restrict__ W5,
    const float* __restrict__ W6, const float* __restrict__ W7,
    ushort_t* __restrict__ frag) {
  const int idx = blockIdx.x * 256 + threadIdx.x;   // 8 mats * 512 entries
  if (idx >= 8 * 512) return;
  const int lane = idx & 63;
  const int h = (idx >> 6) & 1;
  const int t = (idx >> 7) & 3;
  const int mat = idx >> 9;
  const float* W = mat == 0 ? W0 : mat == 1 ? W1 : mat == 2 ? W2 : mat == 3 ? W3
                 : mat == 4 ? W4 : mat == 5 ? W5 : mat == 6 ? W6 : W7;
  const int col = t * 16 + (lane & 15);
  const int kb = h * 32 + (lane >> 4) * 8;
#pragma unroll
  for (int j = 0; j < 8; ++j)
    frag[(size_t)idx * 8 + j] = f2bf(W[(kb + j) * D + col]);
}

// ---------------------------------------------------------------------------
// K1: per-block bucket histogram (both directions), LDS atomics only.
// ---------------------------------------------------------------------------
__global__ __launch_bounds__(256) void hist_k(const int* __restrict__ uidx,
                                              const int* __restrict__ midx,
                                              int* __restrict__ C_u,
                                              int* __restrict__ C_m) {
  __shared__ int h[NBKT];
  for (int i = threadIdx.x; i < NBKT; i += 256) h[i] = 0;
  __syncthreads();
  const int base = blockIdx.x * CHUNK;
  const int lim = min(base + CHUNK, NE);
  for (int e = base + threadIdx.x; e < lim; e += 256) {
    atomicAdd(&h[uidx[e] >> 7], 1);
    atomicAdd(&h[BU_BKTS + (midx[e] >> 7)], 1);
  }
  __syncthreads();
  for (int i = threadIdx.x; i < BU_BKTS; i += 256) C_u[(size_t)blockIdx.x * BU_BKTS + i] = h[i];
  for (int i = threadIdx.x; i < BM_BKTS; i += 256) C_m[(size_t)blockIdx.x * BM_BKTS + i] = h[BU_BKTS + i];
}

// ---------------------------------------------------------------------------
// K2a: per-bucket exclusive prefix over the 256 blocks; emit bucket totals.
// ---------------------------------------------------------------------------
__global__ __launch_bounds__(256) void colscan_k(int* __restrict__ C_u,
                                                 int* __restrict__ C_m,
                                                 int* __restrict__ tot_u,
                                                 int* __restrict__ tot_m) {
  const int t = blockIdx.x * blockDim.x + threadIdx.x;
  if (t < BU_BKTS) {
    int run = 0;
    for (int blk = 0; blk < NBLK; ++blk) {
      const size_t idx = (size_t)blk * BU_BKTS + t;
      const int v = C_u[idx];
      C_u[idx] = run;
      run += v;
    }
    tot_u[t] = run;
  } else if (t < NBKT) {
    const int b = t - BU_BKTS;
    int run = 0;
    for (int blk = 0; blk < NBLK; ++blk) {
      const size_t idx = (size_t)blk * BM_BKTS + b;
      const int v = C_m[idx];
      C_m[idx] = run;
      run += v;
    }
    tot_m[b] = run;
  }
}

// ---------------------------------------------------------------------------
// K2b: single-block exclusive scans of bucket totals -> bucket bases.
// ---------------------------------------------------------------------------
__device__ void scan_inline(const int* __restrict__ in, int* __restrict__ out,
                            int n, int* partial) {
  const int tid = threadIdx.x;
  const int chunk = (n + 1023) / 1024;
  const int s = tid * chunk;
  const int e = min(s + chunk, n);
  int sum = 0;
  for (int i = s; i < e; ++i) sum += in[i];
  partial[tid] = sum;
  __syncthreads();
  for (int off = 1; off < 1024; off <<= 1) {
    int v = (tid >= off) ? partial[tid - off] : 0;
    __syncthreads();
    if (tid >= off) partial[tid] += v;
    __syncthreads();
  }
  int run = (tid == 0) ? 0 : partial[tid - 1];
  for (int i = s; i < e; ++i) {
    out[i] = run;
    run += in[i];
  }
  if (tid == 1023) out[n] = partial[1023];
}

__global__ __launch_bounds__(1024) void bucketscan_k(const int* __restrict__ tot_u,
                                                     int* __restrict__ bb_u,
                                                     const int* __restrict__ tot_m,
                                                     int* __restrict__ bb_m) {
  __shared__ int partial[1024];
  scan_inline(tot_u, bb_u, BU_BKTS, partial);
  __syncthreads();
  scan_inline(tot_m, bb_m, BM_BKTS, partial);
}

// ---------------------------------------------------------------------------
// K3: partition pass, LDS cursors only. rec = (src << 7) | dstlow.
// ---------------------------------------------------------------------------
__global__ __launch_bounds__(256) void part_k(const int* __restrict__ uidx,
                                              const int* __restrict__ midx,
                                              const int* __restrict__ C_u,
                                              const int* __restrict__ C_m,
                                              const int* __restrict__ bb_u,
                                              const int* __restrict__ bb_m,
                                              int* __restrict__ rec_u,
                                              int* __restrict__ rec_m) {
  __shared__ int cur[NBKT];
  for (int i = threadIdx.x; i < BU_BKTS; i += 256)
    cur[i] = bb_u[i] + C_u[(size_t)blockIdx.x * BU_BKTS + i];
  for (int i = threadIdx.x; i < BM_BKTS; i += 256)
    cur[BU_BKTS + i] = bb_m[i] + C_m[(size_t)blockIdx.x * BM_BKTS + i];
  __syncthreads();
  const int base = blockIdx.x * CHUNK;
  const int lim = min(base + CHUNK, NE);
  for (int e = base + threadIdx.x; e < lim; e += 256) {
    const int u = uidx[e];
    const int m = midx[e];
    const int pu = atomicAdd(&cur[u >> 7], 1);
    rec_u[pu] = (m << 7) | (u & (BDST - 1));
    const int pm = atomicAdd(&cur[BU_BKTS + (m >> 7)], 1);
    rec_m[pm] = (u << 7) | (m & (BDST - 1));
  }
}

// ---------------------------------------------------------------------------
// K4: per-bucket counting sort -> per-node CSR (adj + rowp). LDS atomics only.
// ---------------------------------------------------------------------------
__global__ __launch_bounds__(256) void sort_k(const int* __restrict__ rec_m,
                                              const int* __restrict__ rec_u,
                                              const int* __restrict__ bb_m,
                                              const int* __restrict__ bb_u,
                                              int* __restrict__ adj_m,
                                              int* __restrict__ adj_u,
                                              int* __restrict__ rowp_m,
                                              int* __restrict__ rowp_u) {
  __shared__ int cnt[BDST];
  __shared__ int off[BDST];
  __shared__ int tmp[BDST];
  const bool is_m = (blockIdx.x < BM_BKTS);
  const int bkt = is_m ? blockIdx.x : blockIdx.x - BM_BKTS;
  const int* recs = is_m ? rec_m : rec_u;
  const int* bb   = is_m ? bb_m : bb_u;
  int* adj  = is_m ? adj_m : adj_u;
  int* rowp = is_m ? rowp_m : rowp_u;
  const int nDst = is_m ? NM : NU;
  const int tid = threadIdx.x;

  for (int i = tid; i < BDST; i += 256) cnt[i] = 0;
  __syncthreads();
  const int rbeg = bb[bkt], rend = bb[bkt + 1];
  for (int j = rbeg + tid; j < rend; j += 256)
    atomicAdd(&cnt[recs[j] & (BDST - 1)], 1);
  __syncthreads();

  if (tid < BDST) tmp[tid] = cnt[tid];
  __syncthreads();
  for (int o = 1; o < BDST; o <<= 1) {
    int v = 0;
    if (tid < BDST && tid >= o) v = tmp[tid - o];
    __syncthreads();
    if (tid < BDST && tid >= o) tmp[tid] += v;
    __syncthreads();
  }
  if (tid < BDST) off[tid] = (tid == 0) ? 0 : tmp[tid - 1];
  __syncthreads();

  if (tid < BDST) {
    const int node = bkt * BDST + tid;
    if (node < nDst) rowp[node] = rbeg + off[tid];
  }
  if (blockIdx.x == 0 && tid == 0) rowp_m[NM] = NE;
  if (blockIdx.x == BM_BKTS && tid == 0) rowp_u[NU] = NE;

  if (tid < BDST) cnt[tid] = 0;
  __syncthreads();
  for (int j = rbeg + tid; j < rend; j += 256) {
    const int q = recs[j];
    const int dl = q & (BDST - 1);
    const int pos = atomicAdd(&cnt[dl], 1);
    adj[rbeg + off[dl] + pos] = q >> 7;
  }
}

// ---------------------------------------------------------------------------
// bf16 CSR gather-aggregate, uint2 edition: 16 lanes per edge-row (8 B/lane),
// one wave-load covers 4 edge rows; 16 edges in flight; mean stored bf16.
// ---------------------------------------------------------------------------
__device__ __forceinline__ void agg_node16(const uint2* __restrict__ x2,
                                           const int* __restrict__ rowp,
                                           const int* __restrict__ adj,
                                           uint2* __restrict__ mean_h2,
                                           int node, int g, int q) {
  const int beg = rowp[node];
  const int end = rowp[node + 1];
  float a0 = 0.f, a1 = 0.f, a2 = 0.f, a3 = 0.f;
  int j = beg;
  for (; j + 16 <= end; j += 16) {
    const int e0 = adj[j + g];
    const int e1 = adj[j + 4 + g];
    const int e2 = adj[j + 8 + g];
    const int e3 = adj[j + 12 + g];
    const uint2 p0 = x2[(size_t)e0 * 16 + q];
    const uint2 p1 = x2[(size_t)e1 * 16 + q];
    const uint2 p2 = x2[(size_t)e2 * 16 + q];
    const uint2 p3 = x2[(size_t)e3 * 16 + q];
    a0 += (bflo(p0.x) + bflo(p1.x)) + (bflo(p2.x) + bflo(p3.x));
    a1 += (bfhi(p0.x) + bfhi(p1.x)) + (bfhi(p2.x) + bfhi(p3.x));
    a2 += (bflo(p0.y) + bflo(p1.y)) + (bflo(p2.y) + bflo(p3.y));
    a3 += (bfhi(p0.y) + bfhi(p1.y)) + (bfhi(p2.y) + bfhi(p3.y));
  }
  for (; j + 4 <= end; j += 4) {
    const int e = adj[j + g];
    const uint2 p = x2[(size_t)e * 16 + q];
    a0 += bflo(p.x); a1 += bfhi(p.x); a2 += bflo(p.y); a3 += bfhi(p.y);
  }
  if (j < end && g < end - j) {          // remainder 1..3 edges
    const int e = adj[j + g];
    const uint2 p = x2[(size_t)e * 16 + q];
    a0 += bflo(p.x); a1 += bfhi(p.x); a2 += bflo(p.y); a3 += bfhi(p.y);
  }
  a0 += __shfl_xor(a0, 16); a1 += __shfl_xor(a1, 16);
  a2 += __shfl_xor(a2, 16); a3 += __shfl_xor(a3, 16);
  a0 += __shfl_xor(a0, 32); a1 += __shfl_xor(a1, 32);
  a2 += __shfl_xor(a2, 32); a3 += __shfl_xor(a3, 32);
  if (g == 0) {
    const float inv = 1.0f / fmaxf((float)(end - beg), 1.0f);
    uint2 o;
    o.x = (uint_t)f2bf(a0 * inv) | ((uint_t)f2bf(a1 * inv) << 16);
    o.y = (uint_t)f2bf(a2 * inv) | ((uint_t)f2bf(a3 * inv) << 16);
    mean_h2[(size_t)node * 16 + q] = o;
  }
}

__global__ __launch_bounds__(256) void csr_both_h(const uint2* __restrict__ xu2,
                                                  const uint2* __restrict__ xm2,
                                                  const int* __restrict__ rowp_u,
                                                  const int* __restrict__ rowp_m,
                                                  const int* __restrict__ adj_u,
                                                  const int* __restrict__ adj_m,
                                                  uint2* __restrict__ mean_u2,
                                                  uint2* __restrict__ mean_m2) {
  const int lane = threadIdx.x & 63;
  const int g = lane >> 4;              // edge group 0..3
  const int q = lane & 15;              // uint2 position within row
  const int wid  = (blockIdx.x * blockDim.x + threadIdx.x) >> 6;
  const int W    = (gridDim.x * blockDim.x) >> 6;
  const int WM   = W / 3;
  if (wid < WM) {
    for (int node = wid; node < NM; node += WM)
      agg_node16(xu2, rowp_m, adj_m, mean_m2, node, g, q);
  } else {
    const int uw = wid - WM, UW = W - WM;
    for (int node = uw; node < NU; node += UW)
      agg_node16(xm2, rowp_u, adj_u, mean_u2, node, g, q);
  }
}

// ---------------------------------------------------------------------------
// MFMA node transform: out = [relu]( mean @ Wl + b + x @ Wr )
// wave handles 16 nodes x 64 cols = 16 x mfma_f32_16x16x32_bf16.
// A frag: lane holds row=lane&15, k=(lane>>4)*8+j (+32 for half 1).
// B frag: preswizzled by wprep_k. C/D: row=(lane>>4)*4+j, col=lane&15 (m89).
// mode 1: relu + bf16 out; mode 0: f32 out (d_out).
// ---------------------------------------------------------------------------
__global__ __launch_bounds__(256) void node_mfma_k(
    const ushort_t* __restrict__ mean_u, const ushort_t* __restrict__ mean_m,
    const ushort_t* __restrict__ xu_h,   const ushort_t* __restrict__ xm_h,
    const ushort_t* __restrict__ fragL_um, const ushort_t* __restrict__ fragR_um,
    const ushort_t* __restrict__ fragL_mu, const ushort_t* __restrict__ fragR_mu,
    const float* __restrict__ b_um, const float* __restrict__ b_mu,
    float* __restrict__ outf_u, float* __restrict__ outf_m,
    ushort_t* __restrict__ outh_u, ushort_t* __restrict__ outh_m, int mode) {
  const int lane = threadIdx.x & 63;
  const int wid  = (blockIdx.x * blockDim.x + threadIdx.x) >> 6;
  const int W    = (gridDim.x * blockDim.x) >> 6;
  const int WM   = W / 3;

  const ushort_t *mean, *xh, *fL, *fR;
  const float* bias;
  float* outf;
  ushort_t* outh;
  int nt, t0, tstride;
  if (wid < WM) {               // movies: relation user->movie
    mean = mean_m; xh = xm_h; fL = fragL_um; fR = fragR_um; bias = b_um;
    outf = outf_m; outh = outh_m; nt = NM / 16; t0 = wid; tstride = WM;
  } else {                      // users: relation movie->user
    mean = mean_u; xh = xu_h; fL = fragL_mu; fR = fragR_mu; bias = b_mu;
    outf = outf_u; outh = outh_u; nt = NU / 16; t0 = wid - WM; tstride = W - WM;
  }

  short8_t bl[4][2], br[4][2];
#pragma unroll
  for (int t = 0; t < 4; ++t)
#pragma unroll
    for (int h = 0; h < 2; ++h) {
      bl[t][h] = *(const short8_t*)&fL[(size_t)((t * 2 + h) * 64 + lane) * 8];
      br[t][h] = *(const short8_t*)&fR[(size_t)((t * 2 + h) * 64 + lane) * 8];
    }
  const int colb = lane & 15;
  const int kq = lane >> 4;
  float bv[4];
#pragma unroll
  for (int t = 0; t < 4; ++t) bv[t] = bias[t * 16 + colb];

  for (int tile = t0; tile < nt; tile += tstride) {
    const int base = tile * 16;
    const ushort_t* mrow = mean + (size_t)(base + colb) * D + kq * 8;
    const ushort_t* xrow = xh   + (size_t)(base + colb) * D + kq * 8;
    const short8_t am0 = *(const short8_t*)(mrow);
    const short8_t am1 = *(const short8_t*)(mrow + 32);
    const short8_t ax0 = *(const short8_t*)(xrow);
    const short8_t ax1 = *(const short8_t*)(xrow + 32);
#pragma unroll
    for (int t = 0; t < 4; ++t) {
      f32x4_t acc = {bv[t], bv[t], bv[t], bv[t]};
      acc = __builtin_amdgcn_mfma_f32_16x16x32_bf16(am0, bl[t][0], acc, 0, 0, 0);
      acc = __builtin_amdgcn_mfma_f32_16x16x32_bf16(am1, bl[t][1], acc, 0, 0, 0);
      acc = __builtin_amdgcn_mfma_f32_16x16x32_bf16(ax0, br[t][0], acc, 0, 0, 0);
      acc = __builtin_amdgcn_mfma_f32_16x16x32_bf16(ax1, br[t][1], acc, 0, 0, 0);
      const int col = t * 16 + colb;
#pragma unroll
      for (int j = 0; j < 4; ++j) {
        const int node = base + kq * 4 + j;
        if (mode) {
          outh[(size_t)node * D + col] = f2bf(fmaxf(acc[j], 0.f));
        } else {
          outf[(size_t)node * D + col] = acc[j];
        }
      }
    }
  }
}

// ---------------------------------------------------------------------------
extern "C" void kernel_launch(void* const* d_in, const int* in_sizes, int n_in,
                              void* d_out, int out_size, void* d_ws, size_t ws_size,
                              hipStream_t stream) {
  const float* x_user  = (const float*)d_in[0];
  const float* x_movie = (const float*)d_in[1];
  const float* Wl1_um = (const float*)d_in[2];
  const float* Wr1_um = (const float*)d_in[3];
  const float* b1_um  = (const float*)d_in[4];
  const float* Wl1_mu = (const float*)d_in[5];
  const float* Wr1_mu = (const float*)d_in[6];
  const float* b1_mu  = (const float*)d_in[7];
  const float* Wl2_um = (const float*)d_in[8];
  const float* Wr2_um = (const float*)d_in[9];
  const float* b2_um  = (const float*)d_in[10];
  const float* Wl2_mu = (const float*)d_in[11];
  const float* Wr2_mu = (const float*)d_in[12];
  const float* b2_mu  = (const float*)d_in[13];
  const int* uidx = (const int*)d_in[14];
  const int* midx = (const int*)d_in[15];

  // ---- workspace layout. Aliasing:
  //   rec_* (32 MB, dead after sort_k)  -> inside u1_h+m1_h (38.4 MB)
  //   C_*   (2.4 MB, dead after part_k) -> inside mean_u (25.6 MB)
  char* ws = (char*)d_ws;
  ushort_t* mean_u = (ushort_t*)ws; ws += (size_t)NU * D * sizeof(ushort_t); // 25.6 MB
  ushort_t* mean_m = (ushort_t*)ws; ws += (size_t)NM * D * sizeof(ushort_t); // 12.8 MB
  ushort_t* xu_h = (ushort_t*)ws;   ws += (size_t)NU * D * sizeof(ushort_t); // 25.6 MB
  ushort_t* xm_h = (ushort_t*)ws;   ws += (size_t)NM * D * sizeof(ushort_t); // 12.8 MB
  ushort_t* u1_h = (ushort_t*)ws;   ws += (size_t)NU * D * sizeof(ushort_t); // 25.6 MB
  ushort_t* m1_h = (ushort_t*)ws;   ws += (size_t)NM * D * sizeof(ushort_t); // 12.8 MB
  int* adj_u  = (int*)ws;           ws += (size_t)NE * sizeof(int);          // 16 MB
  int* adj_m  = (int*)ws;           ws += (size_t)NE * sizeof(int);          // 16 MB
  int* rowp_u = (int*)ws;           ws += ((size_t)NU + 1) * sizeof(int);
  int* rowp_m = (int*)ws;           ws += ((size_t)NM + 1) * sizeof(int);
  int* tot_u  = (int*)ws;           ws += (size_t)BU_BKTS * sizeof(int);
  int* tot_m  = (int*)ws;           ws += (size_t)BM_BKTS * sizeof(int);
  int* bb_u   = (int*)ws;           ws += ((size_t)BU_BKTS + 1) * sizeof(int);
  int* bb_m   = (int*)ws;           ws += ((size_t)BM_BKTS + 1) * sizeof(int);
  ushort_t* fragW = (ushort_t*)ws;  ws += (size_t)8 * 512 * 8 * sizeof(ushort_t); // 64 KB

  int* rec_u = (int*)u1_h;                        // 16 MB \ inside u1_h+m1_h
  int* rec_m = rec_u + NE;                        // 16 MB /
  int* C_u   = (int*)mean_u;                      // 1.6 MB \ inside mean_u
  int* C_m   = C_u + (size_t)NBLK * BU_BKTS;      // 0.8 MB /

  float* u2 = (float*)d_out;
  float* m2 = (float*)d_out + (size_t)NU * D;

  const dim3 blk(256);

  // ---- bf16 casts + weight swizzle + CSR build ----
  cast_k<<<2048, blk, 0, stream>>>(x_user, x_movie, xu_h, xm_h);
  wprep_k<<<16, blk, 0, stream>>>(Wl1_um, Wr1_um, Wl1_mu, Wr1_mu,
                                  Wl2_um, Wr2_um, Wl2_mu, Wr2_mu, fragW);
  hist_k<<<NBLK, blk, 0, stream>>>(uidx, midx, C_u, C_m);
  colscan_k<<<(NBKT + 255) / 256, blk, 0, stream>>>(C_u, C_m, tot_u, tot_m);
  bucketscan_k<<<1, 1024, 0, stream>>>(tot_u, bb_u, tot_m, bb_m);
  part_k<<<NBLK, blk, 0, stream>>>(uidx, midx, C_u, C_m, bb_u, bb_m, rec_u, rec_m);
  sort_k<<<NBKT, blk, 0, stream>>>(rec_m, rec_u, bb_m, bb_u,
                                   adj_m, adj_u, rowp_m, rowp_u);

  // ---- layer 1 (relu, outputs bf16 u1_h/m1_h) ----
  csr_both_h<<<3072, blk, 0, stream>>>((const uint2*)xu_h, (const uint2*)xm_h,
                                       rowp_u, rowp_m, adj_u, adj_m,
                                       (uint2*)mean_u, (uint2*)mean_m);
  node_mfma_k<<<1024, blk, 0, stream>>>(mean_u, mean_m, xu_h, xm_h,
                                        fragW + 0 * 4096, fragW + 1 * 4096,
                                        fragW + 2 * 4096, fragW + 3 * 4096,
                                        b1_um, b1_mu,
                                        nullptr, nullptr, u1_h, m1_h, 1);

  // ---- layer 2 (no activation, writes f32 d_out) ----
  csr_both_h<<<3072, blk, 0, stream>>>((const uint2*)u1_h, (const uint2*)m1_h,
                                       rowp_u, rowp_m, adj_u, adj_m,
                                       (uint2*)mean_u, (uint2*)mean_m);
  node_mfma_k<<<1024, blk, 0, stream>>>(mean_u, mean_m, u1_h, m1_h,
                                        fragW + 4 * 4096, fragW + 5 * 4096,
                                        fragW + 6 * 4096, fragW + 7 * 4096,
                                        b2_um, b2_mu,
                                        u2, m2, nullptr, nullptr, 0);
}